// Round 4
// baseline (1265.633 us; speedup 1.0000x reference)
//
#include <hip/hip_runtime.h>
#include <hip/hip_fp16.h>
#include <math.h>

#define NTOK 16384
#define KCB  4096
#define DIM  128
#define NG16 (KCB / 16)   // 256 16-code groups

typedef short bf16x8 __attribute__((ext_vector_type(8)));
typedef float f32x4  __attribute__((ext_vector_type(4)));

// RNE float -> bf16 bits
static __device__ inline unsigned short rne_bf16(float f) {
  unsigned u = __float_as_uint(f);
  return (unsigned short)((u + 0x7FFFu + ((u >> 16) & 1u)) >> 16);
}

// ---------------------------------------------------------------------------
// ws layout (float offsets):
//   [0..2]  accum: 0=mse_sum, 1=cos_sum, 2=pair_sum
//   [3]     minbits (unsigned, +inf init)
//   [16]                sumx2[NTOK]
//   +NTOK               sumc2[KCB]
//   +KCB                absum[NTOK]
//   +NTOK               cnt[KCB] (int)
//   +KCB                code_int[NTOK] (int)
//   +NTOK               cbh[KCB*128] (ushort, bf16 bits)  = 262144 B
//   +131072(f)          gmax16[NG16*NTOK] (ushort, fp16)  = 8.39 MB
// ---------------------------------------------------------------------------

__global__ __launch_bounds__(256) void k_init(float* __restrict__ accum,
                                              unsigned* __restrict__ minbits,
                                              int* __restrict__ cnt) {
  const int t = threadIdx.x;
  if (t < 3) accum[t] = 0.0f;
  if (t == 3) *minbits = 0x7F800000u;  // +inf
  for (int k = t; k < KCB; k += 256) cnt[k] = 0;
}

// codebook fp32 -> bf16 bits (RNE), 8 elems/thread
__global__ __launch_bounds__(256) void k_convert(const float* __restrict__ cb,
                                                 unsigned short* __restrict__ cbh) {
  const int base = (blockIdx.x * 256 + threadIdx.x) * 8;
  float4 v0 = *(const float4*)(cb + base);
  float4 v1 = *(const float4*)(cb + base + 4);
  ushort4 o0, o1;
  o0.x = rne_bf16(v0.x); o0.y = rne_bf16(v0.y); o0.z = rne_bf16(v0.z); o0.w = rne_bf16(v0.w);
  o1.x = rne_bf16(v1.x); o1.y = rne_bf16(v1.y); o1.z = rne_bf16(v1.z); o1.w = rne_bf16(v1.w);
  *(ushort4*)(cbh + base) = o0;
  *(ushort4*)(cbh + base + 4) = o1;
}

// Row sum-of-squares (fp64, one rounding) + sum|x| for latent rows.
__global__ __launch_bounds__(256) void k_rownorm(const float* __restrict__ lat,
                                                 const float* __restrict__ cb,
                                                 float* __restrict__ sumx2,
                                                 float* __restrict__ sumc2,
                                                 float* __restrict__ absum) {
  const int row  = blockIdx.x * 4 + (threadIdx.x >> 6);
  const int lane = threadIdx.x & 63;
  const float* src = (row < NTOK) ? (lat + (size_t)row * DIM)
                                  : (cb + (size_t)(row - NTOK) * DIM);
  float2 v = *(const float2*)(src + lane * 2);
  double s  = (double)v.x * (double)v.x + (double)v.y * (double)v.y;
  double sa = fabs((double)v.x) + fabs((double)v.y);
#pragma unroll
  for (int m = 32; m >= 1; m >>= 1) {
    s  += __shfl_xor(s, m, 64);
    sa += __shfl_xor(sa, m, 64);
  }
  if (lane == 0) {
    if (row < NTOK) { sumx2[row] = (float)s; absum[row] = (float)sa; }
    else            sumc2[row - NTOK] = (float)s;
  }
}

// bf16 MFMA scan: per (token, 16-code group) store fp16(max over group of acc),
// acc = mfma-approx of dot(x, c). Argmin(dist) == argmax(2*dot - ||c||^2); the
// resolve kernel re-evaluates every group within a rigorous error window in
// exact fp32, so this kernel only needs bounded error, not exactness.
// Block: 256 thr = 4 waves; wave = 32 tokens (2 col-tiles); 8 code-tiles of 64.
__global__ __launch_bounds__(256) void k_approx(const float* __restrict__ lat,
                                                const unsigned short* __restrict__ cbh,
                                                unsigned short* __restrict__ gmax16) {
  __shared__ __align__(16) unsigned char smem[16384];  // 64 codes x 128 bf16, swizzled
  const int t = threadIdx.x;
  const int w = t >> 6, l = t & 63;
  const int l15 = l & 15, lq = l >> 4;
  const int tokb = blockIdx.x * 128 + w * 32;
  const int ct0 = blockIdx.y * 8;

  // B-fragments (tokens), built from fp32 with RNE. k-layout (16x16x32):
  // lane l supplies k = lq*4 + (j&3) + 16*(j>>2), col = l15.
  bf16x8 bfr[2][4];
#pragma unroll
  for (int ctile = 0; ctile < 2; ++ctile) {
    const float* row = lat + (size_t)(tokb + ctile * 16 + l15) * DIM;
#pragma unroll
    for (int ks = 0; ks < 4; ++ks) {
      const int d0 = ks * 32 + lq * 4;
      float4 c0 = *(const float4*)(row + d0);
      float4 c1 = *(const float4*)(row + d0 + 16);
      union { ushort4 u4[2]; bf16x8 v; } cv;
      cv.u4[0].x = rne_bf16(c0.x); cv.u4[0].y = rne_bf16(c0.y);
      cv.u4[0].z = rne_bf16(c0.z); cv.u4[0].w = rne_bf16(c0.w);
      cv.u4[1].x = rne_bf16(c1.x); cv.u4[1].y = rne_bf16(c1.y);
      cv.u4[1].z = rne_bf16(c1.z); cv.u4[1].w = rne_bf16(c1.w);
      bfr[ctile][ks] = cv.v;
    }
  }

  for (int it = 0; it < 8; ++it) {
    const int ct = ct0 + it;
    __syncthreads();
    {  // stage 64-code tile, XOR-swizzled 16B chunks (bank-conflict-free reads)
      const int r = t & 63, seg = t >> 6;
      const unsigned short* src = cbh + (size_t)(ct * 64 + r) * DIM + seg * 32;
      const int sw = (r & 7) << 4;
#pragma unroll
      for (int i = 0; i < 4; ++i) {
        uint4 v = *(const uint4*)(src + i * 8);
        *(uint4*)(smem + r * 256 + ((seg * 64 + i * 16) ^ sw)) = v;
      }
    }
    __syncthreads();

#pragma unroll
    for (int rt = 0; rt < 4; ++rt) {
      const int row = rt * 16 + l15;
      const int sw = (row & 7) << 4;
      bf16x8 afr[4];
#pragma unroll
      for (int ks = 0; ks < 4; ++ks) {
        const int off = ks * 64 + lq * 8;
        union { uint2 u2[2]; bf16x8 v; } cv;
        cv.u2[0] = *(const uint2*)(smem + row * 256 + (off ^ sw));
        cv.u2[1] = *(const uint2*)(smem + row * 256 + (((off + 32)) ^ sw));
        afr[ks] = cv.v;
      }
#pragma unroll
      for (int ctile = 0; ctile < 2; ++ctile) {
        f32x4 acc = {0.0f, 0.0f, 0.0f, 0.0f};
#pragma unroll
        for (int ks = 0; ks < 4; ++ks)
          acc = __builtin_amdgcn_mfma_f32_16x16x32_bf16(afr[ks], bfr[ctile][ks], acc, 0, 0, 0);
        // fold 4 regs (codes) then 4 quarters -> max over the 16 codes of rt
        float gm = fmaxf(fmaxf(acc[0], acc[1]), fmaxf(acc[2], acc[3]));
        gm = fmaxf(gm, __shfl_xor(gm, 16, 64));
        gm = fmaxf(gm, __shfl_xor(gm, 32, 64));
        if (lq == 0) {
          const int tok = tokb + ctile * 16 + l15;
          gmax16[(size_t)(ct * 4 + rt) * NTOK + tok] = __half_as_ushort(__float2half(gm));
        }
      }
    }
  }
}

// Per token: m1 = max group value; exact fp32 re-eval (reference d-ascending
// chain) of all groups within window W; winner by (dist, idx) packed min.
// W >= 4*doterr + max||c||^2 + 2*fp16err + slack:
//   doterr <= absum * cmax * 2^-8 * 1.002 + 1.5e-6,  cmax = 2^-12
//   -> W = absum * 3.8224e-6 + 6.0e-5
__global__ __launch_bounds__(256) void k_resolve(const float* __restrict__ lat,
                                                 const float* __restrict__ cb,
                                                 const float* __restrict__ sumx2,
                                                 const float* __restrict__ sumc2,
                                                 const float* __restrict__ absum,
                                                 const unsigned short* __restrict__ gmax16,
                                                 int* __restrict__ code_int,
                                                 float* __restrict__ idx_out,
                                                 int* __restrict__ cnt) {
  __shared__ float red[16][17];
  __shared__ unsigned long long red64[16][17];
  const int t = threadIdx.x;
  const int tt = t & 15, gc = t >> 4;
  const int tok = blockIdx.x * 16 + tt;

  float m = -INFINITY;
#pragma unroll 4
  for (int i = 0; i < NG16 / 16; ++i) {
    const int g = gc + i * 16;
    m = fmaxf(m, __half2float(__ushort_as_half(gmax16[(size_t)g * NTOK + tok])));
  }
  red[tt][gc] = m;
  __syncthreads();
  if (gc == 0) {
    float mm = red[tt][0];
#pragma unroll
    for (int x = 1; x < 16; ++x) mm = fmaxf(mm, red[tt][x]);
    red[tt][16] = mm;
  }
  __syncthreads();
  const float m1  = red[tt][16];
  const float thr = m1 - (absum[tok] * 3.8224e-6f + 6.0e-5f);
  const float sx  = sumx2[tok];
  const float4* xrow = (const float4*)(lat + (size_t)tok * DIM);

  unsigned long long bestp = ~0ull;
  for (int i = 0; i < NG16 / 16; ++i) {
    const int g = gc + i * 16;
    const float h = __half2float(__ushort_as_half(gmax16[(size_t)g * NTOK + tok]));
    if (h >= thr) {
      for (int r = 0; r < 16; ++r) {
        const int code = g * 16 + r;
        const float4* crow = (const float4*)(cb + (size_t)code * DIM);
        float acc = 0.0f;
#pragma unroll 8
        for (int ch = 0; ch < 32; ++ch) {
          const float4 c = crow[ch], x = xrow[ch];
          acc = fmaf(x.x, c.x, acc); acc = fmaf(x.y, c.y, acc);
          acc = fmaf(x.z, c.z, acc); acc = fmaf(x.w, c.w, acc);
        }
        const float dist = (sx - 2.0f * acc) + sumc2[code];
        const unsigned long long p =
            ((unsigned long long)__float_as_uint(dist) << 32) | (unsigned)code;
        bestp = (p < bestp) ? p : bestp;
      }
    }
  }
  red64[tt][gc] = bestp;
  __syncthreads();
  if (gc == 0) {
    unsigned long long bp = red64[tt][0];
#pragma unroll
    for (int x = 1; x < 16; ++x) bp = (red64[tt][x] < bp) ? red64[tt][x] : bp;
    const int code = (int)(bp & 0xFFFFFFFFull);
    code_int[tok] = code;
    idx_out[tok] = (float)code;
    atomicAdd(&cnt[code], 1);
  }
}

// Gather quantized_st + mse + sel_cos partials.
__global__ __launch_bounds__(256) void k_gather(const float* __restrict__ lat,
                                                const float* __restrict__ cb,
                                                const float* __restrict__ sumx2,
                                                const float* __restrict__ sumc2,
                                                const int* __restrict__ code_int,
                                                float* __restrict__ qout,
                                                float* __restrict__ accum) {
  const int wave = threadIdx.x >> 6, lane = threadIdx.x & 63;
  __shared__ float sm[8];
  float msel = 0.0f, cosl = 0.0f;
  const int base = blockIdx.x * 64 + wave * 16;
  for (int it = 0; it < 16; ++it) {
    const int tok = base + it;
    const int code = code_int[tok];
    float2 l2 = *(const float2*)(lat + (size_t)tok * DIM + lane * 2);
    float2 c2 = *(const float2*)(cb + (size_t)code * DIM + lane * 2);
    const float o0 = l2.x + (c2.x - l2.x);
    const float o1 = l2.y + (c2.y - l2.y);
    *(float2*)(qout + (size_t)tok * DIM + lane * 2) = make_float2(o0, o1);
    const float e0 = l2.x - c2.x, e1 = l2.y - c2.y;
    msel += e0 * e0 + e1 * e1;
    float dt = l2.x * c2.x + l2.y * c2.y;
#pragma unroll
    for (int m = 32; m >= 1; m >>= 1) dt += __shfl_xor(dt, m, 64);
    if (lane == 0) {
      const float nx = fmaxf(sqrtf(sumx2[tok]), 1e-12f);
      const float nc = fmaxf(sqrtf(sumc2[code]), 1e-12f);
      cosl += dt / (nx * nc);
    }
  }
#pragma unroll
  for (int m = 32; m >= 1; m >>= 1) msel += __shfl_xor(msel, m, 64);
  if (lane == 0) { sm[wave] = msel; sm[4 + wave] = cosl; }
  __syncthreads();
  if (threadIdx.x == 0) {
    atomicAdd(&accum[0], sm[0] + sm[1] + sm[2] + sm[3]);
    atomicAdd(&accum[1], sm[4] + sm[5] + sm[6] + sm[7]);
  }
}

// Codebook pairwise distances: 128x128 tiles, upper-triangular (x2 off-diag).
#define TILE 128
__global__ __launch_bounds__(256, 2) void k_pair(const float* __restrict__ cb,
                                                 const float* __restrict__ sumc2,
                                                 float* __restrict__ accum,
                                                 unsigned* __restrict__ minbits) {
  const int bj = blockIdx.y, bk = blockIdx.x;
  if (bj > bk) return;
  __shared__ __align__(16) unsigned char smem[66560 + 512];
  float (*Cj)[TILE] = (float (*)[TILE])smem;
  float (*Ck)[TILE] = (float (*)[TILE])(smem + 32768);
  float* qj = (float*)(smem + 65536);
  float* qk = (float*)(smem + 66048);

  const int t  = threadIdx.x;
  const int tx = t & 15, ty = t >> 4;
  const int r_stage = t & 127;
  const int h_stage = t >> 7;

  float acc[8][8];
#pragma unroll
  for (int a = 0; a < 8; ++a)
#pragma unroll
    for (int b = 0; b < 8; ++b) acc[a][b] = 0.0f;

  for (int dc = 0; dc < DIM; dc += 64) {
    __syncthreads();
    {
      const float* jsrc = cb + (size_t)(bj * TILE + r_stage) * DIM + dc + h_stage * 32;
#pragma unroll
      for (int p = 0; p < 8; ++p) {
        float4 v = *(const float4*)(jsrc + p * 4);
        const int d = h_stage * 32 + p * 4;
        Cj[d + 0][r_stage] = v.x; Cj[d + 1][r_stage] = v.y;
        Cj[d + 2][r_stage] = v.z; Cj[d + 3][r_stage] = v.w;
      }
      const float* ksrc = cb + (size_t)(bk * TILE + r_stage) * DIM + dc + h_stage * 32;
#pragma unroll
      for (int p = 0; p < 8; ++p) {
        float4 v = *(const float4*)(ksrc + p * 4);
        const int d = h_stage * 32 + p * 4;
        Ck[d + 0][r_stage] = v.x; Ck[d + 1][r_stage] = v.y;
        Ck[d + 2][r_stage] = v.z; Ck[d + 3][r_stage] = v.w;
      }
      if (dc == 0) {
        if (t < TILE) qj[t] = sumc2[bj * TILE + t];
        else          qk[t - TILE] = sumc2[bk * TILE + (t - TILE)];
      }
    }
    __syncthreads();

#pragma unroll 4
    for (int d = 0; d < 64; ++d) {
      float4 a0 = *(const float4*)&Cj[d][ty * 4];
      float4 a1 = *(const float4*)&Cj[d][64 + ty * 4];
      float4 b0 = *(const float4*)&Ck[d][tx * 4];
      float4 b1 = *(const float4*)&Ck[d][64 + tx * 4];
      const float aa[8] = {a0.x, a0.y, a0.z, a0.w, a1.x, a1.y, a1.z, a1.w};
      const float bb[8] = {b0.x, b0.y, b0.z, b0.w, b1.x, b1.y, b1.z, b1.w};
#pragma unroll
      for (int a = 0; a < 8; ++a)
#pragma unroll
        for (int b = 0; b < 8; ++b)
          acc[a][b] = fmaf(aa[a], bb[b], acc[a][b]);
    }
  }

  float lsum = 0.0f, lmin = INFINITY;
#pragma unroll
  for (int a = 0; a < 8; ++a) {
#pragma unroll
    for (int b = 0; b < 8; ++b) {
      const int jl = ty * 4 + (a & 3) + ((a >> 2) << 6);
      const int kl = tx * 4 + (b & 3) + ((b >> 2) << 6);
      const int j = bj * TILE + jl;
      const int k = bk * TILE + kl;
      const float d2 = (qj[jl] + qk[kl]) - 2.0f * acc[a][b];
      const float dd = sqrtf(fmaxf(d2, 0.0f));
      lsum += dd;
      if (j != k) lmin = fminf(lmin, dd);
    }
  }
  const float scale = (bj == bk) ? 1.0f : 2.0f;

  __syncthreads();
  float* reds = (float*)smem;
  reds[t] = lsum;
  __syncthreads();
  for (int s = 128; s >= 1; s >>= 1) {
    if (t < s) reds[t] += reds[t + s];
    __syncthreads();
  }
  if (t == 0) atomicAdd(&accum[2], reds[0] * scale);
  __syncthreads();
  reds[t] = lmin;
  __syncthreads();
  for (int s = 128; s >= 1; s >>= 1) {
    if (t < s) reds[t] = fminf(reds[t], reds[t + s]);
    __syncthreads();
  }
  if (t == 0) atomicMin(minbits, __float_as_uint(reds[0]));
}

__global__ __launch_bounds__(256) void k_final(const int* __restrict__ cnt,
                                               const float* __restrict__ accum,
                                               const unsigned* __restrict__ minbits,
                                               float* __restrict__ outs) {
  __shared__ float sh[256];
  const int t = threadIdx.x;
  float ent = 0.0f;
  for (int k = t; k < KCB; k += 256) {
    const float p = (float)cnt[k] * (1.0f / (float)NTOK);
    ent += p * logf(p + 1e-10f);
  }
  sh[t] = ent;
  __syncthreads();
  for (int s = 128; s >= 1; s >>= 1) {
    if (t < s) sh[t] += sh[t + s];
    __syncthreads();
  }
  if (t == 0) {
    const float mse = accum[0] * (1.0f / (float)(NTOK * DIM));
    outs[0] = 0.25f * mse;
    outs[1] = mse;
    outs[2] = expf(-sh[0]);
    outs[3] = accum[1] * (1.0f / (float)NTOK);
    outs[4] = accum[2] / ((float)KCB * (float)(KCB - 1));
    outs[5] = __uint_as_float(*minbits);
  }
}

extern "C" void kernel_launch(void* const* d_in, const int* in_sizes, int n_in,
                              void* d_out, int out_size, void* d_ws, size_t ws_size,
                              hipStream_t stream) {
  const float* lat = (const float*)d_in[0];
  const float* cb  = (const float*)d_in[1];

  float* out     = (float*)d_out;
  float* qout    = out;
  float* idx_out = out + (size_t)NTOK * DIM;
  float* outs    = idx_out + NTOK;

  float* W        = (float*)d_ws;
  float* accum    = W;
  unsigned* minb  = (unsigned*)(W + 3);
  float* sumx2    = W + 16;                       // NTOK
  float* sumc2    = sumx2 + NTOK;                 // KCB
  float* absum    = sumc2 + KCB;                  // NTOK
  int*   cnt      = (int*)(absum + NTOK);         // KCB
  int*   code_int = cnt + KCB;                    // NTOK
  unsigned short* cbh    = (unsigned short*)(code_int + NTOK);   // KCB*DIM
  unsigned short* gmax16 = cbh + (size_t)KCB * DIM;              // NG16*NTOK

  hipLaunchKernelGGL(k_init, dim3(1), dim3(256), 0, stream, accum, minb, cnt);
  hipLaunchKernelGGL(k_convert, dim3(KCB * DIM / (256 * 8)), dim3(256), 0, stream, cb, cbh);
  hipLaunchKernelGGL(k_rownorm, dim3((NTOK + KCB) / 4), dim3(256), 0, stream,
                     lat, cb, sumx2, sumc2, absum);
  hipLaunchKernelGGL(k_approx, dim3(NTOK / 128, 8), dim3(256), 0, stream,
                     lat, cbh, gmax16);
  hipLaunchKernelGGL(k_resolve, dim3(NTOK / 16), dim3(256), 0, stream,
                     lat, cb, sumx2, sumc2, absum, gmax16, code_int, idx_out, cnt);
  hipLaunchKernelGGL(k_gather, dim3(NTOK / 64), dim3(256), 0, stream,
                     lat, cb, sumx2, sumc2, code_int, qout, accum);
  hipLaunchKernelGGL(k_pair, dim3(KCB / TILE, KCB / TILE), dim3(256), 0, stream,
                     cb, sumc2, accum, minb);
  hipLaunchKernelGGL(k_final, dim3(1), dim3(256), 0, stream, cnt, accum, minb, outs);
}

// Round 5
// 585.039 us; speedup vs baseline: 2.1633x; 2.1633x over previous
//
#include <hip/hip_runtime.h>
#include <hip/hip_fp16.h>
#include <math.h>

#define NTOK 16384
#define KCB  4096
#define DIM  128
#define NG16 (KCB / 16)     // 256 16-code groups
#define QCAP (1 << 20)      // candidate queue capacity (expected ~48k)

typedef short bf16x8 __attribute__((ext_vector_type(8)));
typedef float f32x4  __attribute__((ext_vector_type(4)));

// RNE float -> bf16 bits
static __device__ inline unsigned short rne_bf16(float f) {
  unsigned u = __float_as_uint(f);
  return (unsigned short)((u + 0x7FFFu + ((u >> 16) & 1u)) >> 16);
}

// ---------------------------------------------------------------------------
// ws layout (float offsets):
//   [0..2] accum: 0=mse_sum, 1=cos_sum, 2=pair_sum
//   [3]    minbits (unsigned, +inf init)
//   [4]    qcount (unsigned)
//   [16]        sumx2[NTOK]
//   +NTOK       sumc2[KCB]
//   +KCB        absum[NTOK]
//   +NTOK       cnt[KCB] (int)
//   +KCB        best[NTOK] (u64 packed (dist_bits<<32)|idx)
//   +2*NTOK     cbh[KCB*DIM] (ushort bf16)
//   +KCB*DIM/2  gmax16[NG16*NTOK] (ushort fp16)
//   +...        queue[QCAP] (uint: tok*256+g)
// ---------------------------------------------------------------------------

__global__ __launch_bounds__(256) void k_init(float* __restrict__ accum,
                                              unsigned* __restrict__ minbits,
                                              unsigned* __restrict__ qcount,
                                              int* __restrict__ cnt,
                                              unsigned long long* __restrict__ best) {
  const int t = threadIdx.x;
  if (t < 3) accum[t] = 0.0f;
  if (t == 3) *minbits = 0x7F800000u;
  if (t == 4) *qcount = 0u;
  for (int k = t; k < KCB; k += 256) cnt[k] = 0;
  for (int i = t; i < NTOK; i += 256) best[i] = 0xFFFFFFFFFFFFFFFFull;
}

__global__ __launch_bounds__(256) void k_convert(const float* __restrict__ cb,
                                                 unsigned short* __restrict__ cbh) {
  const int base = (blockIdx.x * 256 + threadIdx.x) * 8;
  float4 v0 = *(const float4*)(cb + base);
  float4 v1 = *(const float4*)(cb + base + 4);
  ushort4 o0, o1;
  o0.x = rne_bf16(v0.x); o0.y = rne_bf16(v0.y); o0.z = rne_bf16(v0.z); o0.w = rne_bf16(v0.w);
  o1.x = rne_bf16(v1.x); o1.y = rne_bf16(v1.y); o1.z = rne_bf16(v1.z); o1.w = rne_bf16(v1.w);
  *(ushort4*)(cbh + base) = o0;
  *(ushort4*)(cbh + base + 4) = o1;
}

__global__ __launch_bounds__(256) void k_rownorm(const float* __restrict__ lat,
                                                 const float* __restrict__ cb,
                                                 float* __restrict__ sumx2,
                                                 float* __restrict__ sumc2,
                                                 float* __restrict__ absum) {
  const int row  = blockIdx.x * 4 + (threadIdx.x >> 6);
  const int lane = threadIdx.x & 63;
  const float* src = (row < NTOK) ? (lat + (size_t)row * DIM)
                                  : (cb + (size_t)(row - NTOK) * DIM);
  float2 v = *(const float2*)(src + lane * 2);
  double s  = (double)v.x * (double)v.x + (double)v.y * (double)v.y;
  double sa = fabs((double)v.x) + fabs((double)v.y);
#pragma unroll
  for (int m = 32; m >= 1; m >>= 1) {
    s  += __shfl_xor(s, m, 64);
    sa += __shfl_xor(sa, m, 64);
  }
  if (lane == 0) {
    if (row < NTOK) { sumx2[row] = (float)s; absum[row] = (float)sa; }
    else            sumc2[row - NTOK] = (float)s;
  }
}

// bf16 MFMA scan (unchanged from R4 -> identical gmax16 bits -> identical
// candidate sets -> reproduces the verified winners).
__global__ __launch_bounds__(256) void k_approx(const float* __restrict__ lat,
                                                const unsigned short* __restrict__ cbh,
                                                unsigned short* __restrict__ gmax16) {
  __shared__ __align__(16) unsigned char smem[16384];
  const int t = threadIdx.x;
  const int w = t >> 6, l = t & 63;
  const int l15 = l & 15, lq = l >> 4;
  const int tokb = blockIdx.x * 128 + w * 32;
  const int ct0 = blockIdx.y * 8;

  bf16x8 bfr[2][4];
#pragma unroll
  for (int ctile = 0; ctile < 2; ++ctile) {
    const float* row = lat + (size_t)(tokb + ctile * 16 + l15) * DIM;
#pragma unroll
    for (int ks = 0; ks < 4; ++ks) {
      const int d0 = ks * 32 + lq * 4;
      float4 c0 = *(const float4*)(row + d0);
      float4 c1 = *(const float4*)(row + d0 + 16);
      union { ushort4 u4[2]; bf16x8 v; } cv;
      cv.u4[0].x = rne_bf16(c0.x); cv.u4[0].y = rne_bf16(c0.y);
      cv.u4[0].z = rne_bf16(c0.z); cv.u4[0].w = rne_bf16(c0.w);
      cv.u4[1].x = rne_bf16(c1.x); cv.u4[1].y = rne_bf16(c1.y);
      cv.u4[1].z = rne_bf16(c1.z); cv.u4[1].w = rne_bf16(c1.w);
      bfr[ctile][ks] = cv.v;
    }
  }

  for (int it = 0; it < 8; ++it) {
    const int ct = ct0 + it;
    __syncthreads();
    {
      const int r = t & 63, seg = t >> 6;
      const unsigned short* src = cbh + (size_t)(ct * 64 + r) * DIM + seg * 32;
      const int sw = (r & 7) << 4;
#pragma unroll
      for (int i = 0; i < 4; ++i) {
        uint4 v = *(const uint4*)(src + i * 8);
        *(uint4*)(smem + r * 256 + ((seg * 64 + i * 16) ^ sw)) = v;
      }
    }
    __syncthreads();

#pragma unroll
    for (int rt = 0; rt < 4; ++rt) {
      const int row = rt * 16 + l15;
      const int sw = (row & 7) << 4;
      bf16x8 afr[4];
#pragma unroll
      for (int ks = 0; ks < 4; ++ks) {
        const int off = ks * 64 + lq * 8;
        union { uint2 u2[2]; bf16x8 v; } cv;
        cv.u2[0] = *(const uint2*)(smem + row * 256 + (off ^ sw));
        cv.u2[1] = *(const uint2*)(smem + row * 256 + (((off + 32)) ^ sw));
        afr[ks] = cv.v;
      }
#pragma unroll
      for (int ctile = 0; ctile < 2; ++ctile) {
        f32x4 acc = {0.0f, 0.0f, 0.0f, 0.0f};
#pragma unroll
        for (int ks = 0; ks < 4; ++ks)
          acc = __builtin_amdgcn_mfma_f32_16x16x32_bf16(afr[ks], bfr[ctile][ks], acc, 0, 0, 0);
        float gm = fmaxf(fmaxf(acc[0], acc[1]), fmaxf(acc[2], acc[3]));
        gm = fmaxf(gm, __shfl_xor(gm, 16, 64));
        gm = fmaxf(gm, __shfl_xor(gm, 32, 64));
        if (lq == 0) {
          const int tok = tokb + ctile * 16 + l15;
          gmax16[(size_t)(ct * 4 + rt) * NTOK + tok] = __half_as_ushort(__float2half(gm));
        }
      }
    }
  }
}

// Stage A of resolve: per token m1 + threshold (bit-identical to R4), emit
// candidate (tok,group) items to a global queue. Every token emits >=1 item
// (its m1 group always passes thr since W > 0).
__global__ __launch_bounds__(256) void k_resolve_a(const float* __restrict__ absum,
                                                   const unsigned short* __restrict__ gmax16,
                                                   unsigned* __restrict__ qcount,
                                                   unsigned* __restrict__ queue) {
  __shared__ float red[4][64];
  __shared__ float m1s[64];
  const int t = threadIdx.x;
  const int tt = t & 63, gc = t >> 6;   // token-in-block, group-chunk
  const int tok = blockIdx.x * 64 + tt;

  float m = -INFINITY;
#pragma unroll 8
  for (int i = 0; i < 64; ++i) {
    const int g = gc * 64 + i;
    m = fmaxf(m, __half2float(__ushort_as_half(gmax16[(size_t)g * NTOK + tok])));
  }
  red[gc][tt] = m;
  __syncthreads();
  if (gc == 0) {
    m1s[tt] = fmaxf(fmaxf(red[0][tt], red[1][tt]), fmaxf(red[2][tt], red[3][tt]));
  }
  __syncthreads();
  const float thr = m1s[tt] - (absum[tok] * 3.8224e-6f + 6.0e-5f);

#pragma unroll 8
  for (int i = 0; i < 64; ++i) {
    const int g = gc * 64 + i;
    const float h = __half2float(__ushort_as_half(gmax16[(size_t)g * NTOK + tok]));
    if (h >= thr) {
      const unsigned pos = atomicAdd(qcount, 1u);
      if (pos < QCAP) queue[pos] = ((unsigned)tok << 8) | (unsigned)g;
    }
  }
}

// Stage B: dense exact re-eval. Wave takes 4 items; 64 lanes = 4 items x 16
// codes; each lane runs the reference d-ascending fp32 fmaf chain for its
// code (bit-identical to R1-R4). 16-lane min-reduce, one atomicMin per item.
__global__ __launch_bounds__(256) void k_resolve_b(const float* __restrict__ lat,
                                                   const float* __restrict__ cb,
                                                   const float* __restrict__ sumx2,
                                                   const float* __restrict__ sumc2,
                                                   const unsigned* __restrict__ qcount,
                                                   const unsigned* __restrict__ queue,
                                                   unsigned long long* __restrict__ best) {
  const int t = threadIdx.x;
  const int wave = t >> 6, l = t & 63;
  const int sub = l >> 4, cl = l & 15;            // item-slot in wave, code lane
  const unsigned qn = min(*qcount, (unsigned)QCAP);
  const int nwaves = gridDim.x * 4;
  const int wid = blockIdx.x * 4 + wave;

  for (unsigned base = (unsigned)wid * 4; base < qn; base += (unsigned)nwaves * 4) {
    const unsigned ii = base + (unsigned)sub;
    unsigned long long pack = ~0ull;
    int tok = -1;
    if (ii < qn) {
      const unsigned item = queue[ii];
      tok = (int)(item >> 8);
      const int g = (int)(item & 0xFFu);
      const int code = g * 16 + cl;
      const float4* xrow = (const float4*)(lat + (size_t)tok * DIM);
      const float4* crow = (const float4*)(cb + (size_t)code * DIM);
      float acc = 0.0f;
#pragma unroll 8
      for (int ch = 0; ch < 32; ++ch) {
        const float4 c = crow[ch], x = xrow[ch];
        acc = fmaf(x.x, c.x, acc); acc = fmaf(x.y, c.y, acc);
        acc = fmaf(x.z, c.z, acc); acc = fmaf(x.w, c.w, acc);
      }
      const float dist = (sumx2[tok] - 2.0f * acc) + sumc2[code];
      pack = ((unsigned long long)__float_as_uint(dist) << 32) | (unsigned)code;
    }
    // min over the 16 lanes of this item (xor stays within the 16-lane group)
#pragma unroll
    for (int m = 8; m >= 1; m >>= 1) {
      const unsigned long long o = __shfl_xor(pack, m, 64);
      pack = (o < pack) ? o : pack;
    }
    if (cl == 0 && tok >= 0) atomicMin(&best[tok], pack);
  }
}

// Gather quantized_st + mse + sel_cos partials + idx + histogram.
__global__ __launch_bounds__(256) void k_gather(const float* __restrict__ lat,
                                                const float* __restrict__ cb,
                                                const float* __restrict__ sumx2,
                                                const float* __restrict__ sumc2,
                                                const unsigned long long* __restrict__ best,
                                                float* __restrict__ qout,
                                                float* __restrict__ idx_out,
                                                float* __restrict__ accum,
                                                int* __restrict__ cnt) {
  const int wave = threadIdx.x >> 6, lane = threadIdx.x & 63;
  __shared__ float sm[8];
  float msel = 0.0f, cosl = 0.0f;
  const int base = blockIdx.x * 64 + wave * 16;
  for (int it = 0; it < 16; ++it) {
    const int tok = base + it;
    const int code = (int)(best[tok] & 0xFFFFFFFFull);
    float2 l2 = *(const float2*)(lat + (size_t)tok * DIM + lane * 2);
    float2 c2 = *(const float2*)(cb + (size_t)code * DIM + lane * 2);
    const float o0 = l2.x + (c2.x - l2.x);
    const float o1 = l2.y + (c2.y - l2.y);
    *(float2*)(qout + (size_t)tok * DIM + lane * 2) = make_float2(o0, o1);
    const float e0 = l2.x - c2.x, e1 = l2.y - c2.y;
    msel += e0 * e0 + e1 * e1;
    float dt = l2.x * c2.x + l2.y * c2.y;
#pragma unroll
    for (int m = 32; m >= 1; m >>= 1) dt += __shfl_xor(dt, m, 64);
    if (lane == 0) {
      const float nx = fmaxf(sqrtf(sumx2[tok]), 1e-12f);
      const float nc = fmaxf(sqrtf(sumc2[code]), 1e-12f);
      cosl += dt / (nx * nc);
      idx_out[tok] = (float)code;
      atomicAdd(&cnt[code], 1);
    }
  }
#pragma unroll
  for (int m = 32; m >= 1; m >>= 1) msel += __shfl_xor(msel, m, 64);
  if (lane == 0) { sm[wave] = msel; sm[4 + wave] = cosl; }
  __syncthreads();
  if (threadIdx.x == 0) {
    atomicAdd(&accum[0], sm[0] + sm[1] + sm[2] + sm[3]);
    atomicAdd(&accum[1], sm[4] + sm[5] + sm[6] + sm[7]);
  }
}

// Codebook pairwise distances: 128x128 tiles, upper-triangular (x2 off-diag).
#define TILE 128
__global__ __launch_bounds__(256, 2) void k_pair(const float* __restrict__ cb,
                                                 const float* __restrict__ sumc2,
                                                 float* __restrict__ accum,
                                                 unsigned* __restrict__ minbits) {
  const int bj = blockIdx.y, bk = blockIdx.x;
  if (bj > bk) return;
  __shared__ __align__(16) unsigned char smem[66560 + 512];
  float (*Cj)[TILE] = (float (*)[TILE])smem;
  float (*Ck)[TILE] = (float (*)[TILE])(smem + 32768);
  float* qj = (float*)(smem + 65536);
  float* qk = (float*)(smem + 66048);

  const int t  = threadIdx.x;
  const int tx = t & 15, ty = t >> 4;
  const int r_stage = t & 127;
  const int h_stage = t >> 7;

  float acc[8][8];
#pragma unroll
  for (int a = 0; a < 8; ++a)
#pragma unroll
    for (int b = 0; b < 8; ++b) acc[a][b] = 0.0f;

  for (int dc = 0; dc < DIM; dc += 64) {
    __syncthreads();
    {
      const float* jsrc = cb + (size_t)(bj * TILE + r_stage) * DIM + dc + h_stage * 32;
#pragma unroll
      for (int p = 0; p < 8; ++p) {
        float4 v = *(const float4*)(jsrc + p * 4);
        const int d = h_stage * 32 + p * 4;
        Cj[d + 0][r_stage] = v.x; Cj[d + 1][r_stage] = v.y;
        Cj[d + 2][r_stage] = v.z; Cj[d + 3][r_stage] = v.w;
      }
      const float* ksrc = cb + (size_t)(bk * TILE + r_stage) * DIM + dc + h_stage * 32;
#pragma unroll
      for (int p = 0; p < 8; ++p) {
        float4 v = *(const float4*)(ksrc + p * 4);
        const int d = h_stage * 32 + p * 4;
        Ck[d + 0][r_stage] = v.x; Ck[d + 1][r_stage] = v.y;
        Ck[d + 2][r_stage] = v.z; Ck[d + 3][r_stage] = v.w;
      }
      if (dc == 0) {
        if (t < TILE) qj[t] = sumc2[bj * TILE + t];
        else          qk[t - TILE] = sumc2[bk * TILE + (t - TILE)];
      }
    }
    __syncthreads();

#pragma unroll 4
    for (int d = 0; d < 64; ++d) {
      float4 a0 = *(const float4*)&Cj[d][ty * 4];
      float4 a1 = *(const float4*)&Cj[d][64 + ty * 4];
      float4 b0 = *(const float4*)&Ck[d][tx * 4];
      float4 b1 = *(const float4*)&Ck[d][64 + tx * 4];
      const float aa[8] = {a0.x, a0.y, a0.z, a0.w, a1.x, a1.y, a1.z, a1.w};
      const float bb[8] = {b0.x, b0.y, b0.z, b0.w, b1.x, b1.y, b1.z, b1.w};
#pragma unroll
      for (int a = 0; a < 8; ++a)
#pragma unroll
        for (int b = 0; b < 8; ++b)
          acc[a][b] = fmaf(aa[a], bb[b], acc[a][b]);
    }
  }

  float lsum = 0.0f, lmin = INFINITY;
#pragma unroll
  for (int a = 0; a < 8; ++a) {
#pragma unroll
    for (int b = 0; b < 8; ++b) {
      const int jl = ty * 4 + (a & 3) + ((a >> 2) << 6);
      const int kl = tx * 4 + (b & 3) + ((b >> 2) << 6);
      const int j = bj * TILE + jl;
      const int k = bk * TILE + kl;
      const float d2 = (qj[jl] + qk[kl]) - 2.0f * acc[a][b];
      const float dd = sqrtf(fmaxf(d2, 0.0f));
      lsum += dd;
      if (j != k) lmin = fminf(lmin, dd);
    }
  }
  const float scale = (bj == bk) ? 1.0f : 2.0f;

  __syncthreads();
  float* reds = (float*)smem;
  reds[t] = lsum;
  __syncthreads();
  for (int s = 128; s >= 1; s >>= 1) {
    if (t < s) reds[t] += reds[t + s];
    __syncthreads();
  }
  if (t == 0) atomicAdd(&accum[2], reds[0] * scale);
  __syncthreads();
  reds[t] = lmin;
  __syncthreads();
  for (int s = 128; s >= 1; s >>= 1) {
    if (t < s) reds[t] = fminf(reds[t], reds[t + s]);
    __syncthreads();
  }
  if (t == 0) atomicMin(minbits, __float_as_uint(reds[0]));
}

__global__ __launch_bounds__(256) void k_final(const int* __restrict__ cnt,
                                               const float* __restrict__ accum,
                                               const unsigned* __restrict__ minbits,
                                               float* __restrict__ outs) {
  __shared__ float sh[256];
  const int t = threadIdx.x;
  float ent = 0.0f;
  for (int k = t; k < KCB; k += 256) {
    const float p = (float)cnt[k] * (1.0f / (float)NTOK);
    ent += p * logf(p + 1e-10f);
  }
  sh[t] = ent;
  __syncthreads();
  for (int s = 128; s >= 1; s >>= 1) {
    if (t < s) sh[t] += sh[t + s];
    __syncthreads();
  }
  if (t == 0) {
    const float mse = accum[0] * (1.0f / (float)(NTOK * DIM));
    outs[0] = 0.25f * mse;
    outs[1] = mse;
    outs[2] = expf(-sh[0]);
    outs[3] = accum[1] * (1.0f / (float)NTOK);
    outs[4] = accum[2] / ((float)KCB * (float)(KCB - 1));
    outs[5] = __uint_as_float(*minbits);
  }
}

extern "C" void kernel_launch(void* const* d_in, const int* in_sizes, int n_in,
                              void* d_out, int out_size, void* d_ws, size_t ws_size,
                              hipStream_t stream) {
  const float* lat = (const float*)d_in[0];
  const float* cb  = (const float*)d_in[1];

  float* out     = (float*)d_out;
  float* qout    = out;
  float* idx_out = out + (size_t)NTOK * DIM;
  float* outs    = idx_out + NTOK;

  float* W        = (float*)d_ws;
  float* accum    = W;
  unsigned* minb  = (unsigned*)(W + 3);
  unsigned* qcnt  = (unsigned*)(W + 4);
  float* sumx2    = W + 16;                        // NTOK
  float* sumc2    = sumx2 + NTOK;                  // KCB
  float* absum    = sumc2 + KCB;                   // NTOK
  int*   cnt      = (int*)(absum + NTOK);          // KCB
  unsigned long long* best = (unsigned long long*)(cnt + KCB);   // NTOK u64
  unsigned short* cbh    = (unsigned short*)(best + NTOK);       // KCB*DIM
  unsigned short* gmax16 = cbh + (size_t)KCB * DIM;              // NG16*NTOK
  unsigned* queue = (unsigned*)(gmax16 + (size_t)NG16 * NTOK);   // QCAP

  hipLaunchKernelGGL(k_init, dim3(1), dim3(256), 0, stream, accum, minb, qcnt, cnt, best);
  hipLaunchKernelGGL(k_convert, dim3(KCB * DIM / (256 * 8)), dim3(256), 0, stream, cb, cbh);
  hipLaunchKernelGGL(k_rownorm, dim3((NTOK + KCB) / 4), dim3(256), 0, stream,
                     lat, cb, sumx2, sumc2, absum);
  hipLaunchKernelGGL(k_approx, dim3(NTOK / 128, 8), dim3(256), 0, stream,
                     lat, cbh, gmax16);
  hipLaunchKernelGGL(k_resolve_a, dim3(NTOK / 64), dim3(256), 0, stream,
                     absum, gmax16, qcnt, queue);
  hipLaunchKernelGGL(k_resolve_b, dim3(512), dim3(256), 0, stream,
                     lat, cb, sumx2, sumc2, qcnt, queue, best);
  hipLaunchKernelGGL(k_gather, dim3(NTOK / 64), dim3(256), 0, stream,
                     lat, cb, sumx2, sumc2, best, qout, idx_out, accum, cnt);
  hipLaunchKernelGGL(k_pair, dim3(KCB / TILE, KCB / TILE), dim3(256), 0, stream,
                     cb, sumc2, accum, minb);
  hipLaunchKernelGGL(k_final, dim3(1), dim3(256), 0, stream, cnt, accum, minb, outs);
}

// Round 6
// 207.584 us; speedup vs baseline: 6.0970x; 2.8183x over previous
//
#include <hip/hip_runtime.h>
#include <hip/hip_fp16.h>
#include <math.h>

#define NTOK 16384
#define KCB  4096
#define DIM  128
#define NG16 (KCB / 16)     // 256 16-code groups

typedef short bf16x8 __attribute__((ext_vector_type(8)));
typedef float f32x4  __attribute__((ext_vector_type(4)));

// RNE float -> bf16 bits
static __device__ inline unsigned short rne_bf16(float f) {
  unsigned u = __float_as_uint(f);
  return (unsigned short)((u + 0x7FFFu + ((u >> 16) & 1u)) >> 16);
}

// ---------------------------------------------------------------------------
// ws layout (float offsets):
//   [0..2] accum: 0=mse_sum, 1=cos_sum, 2=pair_sum
//   [3]    minbits (unsigned, +inf init)
//   [16]        sumx2[NTOK]
//   +NTOK       sumc2[KCB]
//   +KCB        absum[NTOK]
//   +NTOK       cnt[KCB] (int)
//   +KCB        best[NTOK] (u64 packed (dist_bits<<32)|idx)
//   +2*NTOK     cbh[KCB*DIM] (ushort bf16)
//   +KCB*DIM/2  gmax16[NTOK*NG16] (ushort fp16, ROW-major per token)
// ---------------------------------------------------------------------------

__global__ __launch_bounds__(256) void k_init(float* __restrict__ accum,
                                              unsigned* __restrict__ minbits,
                                              int* __restrict__ cnt) {
  const int t = threadIdx.x;
  if (t < 3) accum[t] = 0.0f;
  if (t == 3) *minbits = 0x7F800000u;
  for (int k = t; k < KCB; k += 256) cnt[k] = 0;
}

__global__ __launch_bounds__(256) void k_convert(const float* __restrict__ cb,
                                                 unsigned short* __restrict__ cbh) {
  const int base = (blockIdx.x * 256 + threadIdx.x) * 8;
  float4 v0 = *(const float4*)(cb + base);
  float4 v1 = *(const float4*)(cb + base + 4);
  ushort4 o0, o1;
  o0.x = rne_bf16(v0.x); o0.y = rne_bf16(v0.y); o0.z = rne_bf16(v0.z); o0.w = rne_bf16(v0.w);
  o1.x = rne_bf16(v1.x); o1.y = rne_bf16(v1.y); o1.z = rne_bf16(v1.z); o1.w = rne_bf16(v1.w);
  *(ushort4*)(cbh + base) = o0;
  *(ushort4*)(cbh + base + 4) = o1;
}

__global__ __launch_bounds__(256) void k_rownorm(const float* __restrict__ lat,
                                                 const float* __restrict__ cb,
                                                 float* __restrict__ sumx2,
                                                 float* __restrict__ sumc2,
                                                 float* __restrict__ absum) {
  const int row  = blockIdx.x * 4 + (threadIdx.x >> 6);
  const int lane = threadIdx.x & 63;
  const float* src = (row < NTOK) ? (lat + (size_t)row * DIM)
                                  : (cb + (size_t)(row - NTOK) * DIM);
  float2 v = *(const float2*)(src + lane * 2);
  double s  = (double)v.x * (double)v.x + (double)v.y * (double)v.y;
  double sa = fabs((double)v.x) + fabs((double)v.y);
#pragma unroll
  for (int m = 32; m >= 1; m >>= 1) {
    s  += __shfl_xor(s, m, 64);
    sa += __shfl_xor(sa, m, 64);
  }
  if (lane == 0) {
    if (row < NTOK) { sumx2[row] = (float)s; absum[row] = (float)sa; }
    else            sumc2[row - NTOK] = (float)s;
  }
}

// bf16 MFMA scan. Values identical to R4/R5 (same MFMA, same reductions, same
// fp16 rounding); only the gmax16 memory layout changed to [tok][group].
__global__ __launch_bounds__(256) void k_approx(const float* __restrict__ lat,
                                                const unsigned short* __restrict__ cbh,
                                                unsigned short* __restrict__ gmax16) {
  __shared__ __align__(16) unsigned char smem[16384];
  const int t = threadIdx.x;
  const int w = t >> 6, l = t & 63;
  const int l15 = l & 15, lq = l >> 4;
  const int tokb = blockIdx.x * 128 + w * 32;
  const int ct0 = blockIdx.y * 8;

  bf16x8 bfr[2][4];
#pragma unroll
  for (int ctile = 0; ctile < 2; ++ctile) {
    const float* row = lat + (size_t)(tokb + ctile * 16 + l15) * DIM;
#pragma unroll
    for (int ks = 0; ks < 4; ++ks) {
      const int d0 = ks * 32 + lq * 4;
      float4 c0 = *(const float4*)(row + d0);
      float4 c1 = *(const float4*)(row + d0 + 16);
      union { ushort4 u4[2]; bf16x8 v; } cv;
      cv.u4[0].x = rne_bf16(c0.x); cv.u4[0].y = rne_bf16(c0.y);
      cv.u4[0].z = rne_bf16(c0.z); cv.u4[0].w = rne_bf16(c0.w);
      cv.u4[1].x = rne_bf16(c1.x); cv.u4[1].y = rne_bf16(c1.y);
      cv.u4[1].z = rne_bf16(c1.z); cv.u4[1].w = rne_bf16(c1.w);
      bfr[ctile][ks] = cv.v;
    }
  }

  for (int it = 0; it < 8; ++it) {
    const int ct = ct0 + it;
    __syncthreads();
    {
      const int r = t & 63, seg = t >> 6;
      const unsigned short* src = cbh + (size_t)(ct * 64 + r) * DIM + seg * 32;
      const int sw = (r & 7) << 4;
#pragma unroll
      for (int i = 0; i < 4; ++i) {
        uint4 v = *(const uint4*)(src + i * 8);
        *(uint4*)(smem + r * 256 + ((seg * 64 + i * 16) ^ sw)) = v;
      }
    }
    __syncthreads();

#pragma unroll
    for (int rt = 0; rt < 4; ++rt) {
      const int row = rt * 16 + l15;
      const int sw = (row & 7) << 4;
      bf16x8 afr[4];
#pragma unroll
      for (int ks = 0; ks < 4; ++ks) {
        const int off = ks * 64 + lq * 8;
        union { uint2 u2[2]; bf16x8 v; } cv;
        cv.u2[0] = *(const uint2*)(smem + row * 256 + (off ^ sw));
        cv.u2[1] = *(const uint2*)(smem + row * 256 + (((off + 32)) ^ sw));
        afr[ks] = cv.v;
      }
#pragma unroll
      for (int ctile = 0; ctile < 2; ++ctile) {
        f32x4 acc = {0.0f, 0.0f, 0.0f, 0.0f};
#pragma unroll
        for (int ks = 0; ks < 4; ++ks)
          acc = __builtin_amdgcn_mfma_f32_16x16x32_bf16(afr[ks], bfr[ctile][ks], acc, 0, 0, 0);
        float gm = fmaxf(fmaxf(acc[0], acc[1]), fmaxf(acc[2], acc[3]));
        gm = fmaxf(gm, __shfl_xor(gm, 16, 64));
        gm = fmaxf(gm, __shfl_xor(gm, 32, 64));
        if (lq == 0) {
          const int tok = tokb + ctile * 16 + l15;
          gmax16[(size_t)tok * NG16 + (ct * 4 + rt)] =
              __half_as_ushort(__float2half(gm));
        }
      }
    }
  }
}

// One wave per token: coalesced 8B/lane gmax row load -> wave max -> threshold
// (bit-identical to R4/R5 => identical candidate set) -> LDS queue -> dense
// exact re-eval (reference d-ascending fp32 chain), register min, single write.
__global__ __launch_bounds__(256) void k_resolve(const float* __restrict__ lat,
                                                 const float* __restrict__ cb,
                                                 const float* __restrict__ sumx2,
                                                 const float* __restrict__ sumc2,
                                                 const float* __restrict__ absum,
                                                 const unsigned short* __restrict__ gmax16,
                                                 unsigned long long* __restrict__ best) {
  __shared__ float xs[4][DIM];
  __shared__ unsigned char q[4][NG16];
  __shared__ int qn[4];
  const int w = threadIdx.x >> 6, l = threadIdx.x & 63;
  const int tok = blockIdx.x * 4 + w;

  if (l == 0) qn[w] = 0;
  {  // stage x row into LDS (broadcast reads later)
    float2 xv = *(const float2*)(lat + (size_t)tok * DIM + l * 2);
    xs[w][l * 2] = xv.x; xs[w][l * 2 + 1] = xv.y;
  }
  const ushort4 hv = *(const ushort4*)(gmax16 + (size_t)tok * NG16 + l * 4);
  const float h0 = __half2float(__ushort_as_half(hv.x));
  const float h1 = __half2float(__ushort_as_half(hv.y));
  const float h2 = __half2float(__ushort_as_half(hv.z));
  const float h3 = __half2float(__ushort_as_half(hv.w));
  float m = fmaxf(fmaxf(h0, h1), fmaxf(h2, h3));
#pragma unroll
  for (int s = 32; s >= 1; s >>= 1) m = fmaxf(m, __shfl_xor(m, s, 64));
  const float thr = m - (absum[tok] * 3.8224e-6f + 6.0e-5f);

  if (h0 >= thr) { const int p = atomicAdd(&qn[w], 1); q[w][p] = (unsigned char)(l * 4 + 0); }
  if (h1 >= thr) { const int p = atomicAdd(&qn[w], 1); q[w][p] = (unsigned char)(l * 4 + 1); }
  if (h2 >= thr) { const int p = atomicAdd(&qn[w], 1); q[w][p] = (unsigned char)(l * 4 + 2); }
  if (h3 >= thr) { const int p = atomicAdd(&qn[w], 1); q[w][p] = (unsigned char)(l * 4 + 3); }
  __syncthreads();

  const int n = qn[w];
  const float sx = sumx2[tok];
  const int sub = l >> 4, cl = l & 15;
  unsigned long long bestp = ~0ull;

  for (int base = 0; base < n; base += 4) {
    unsigned long long pack = ~0ull;
    const int qi = base + sub;
    if (qi < n) {
      const int g = (int)q[w][qi];
      const int code = g * 16 + cl;
      const float4* crow = (const float4*)(cb + (size_t)code * DIM);
      float acc = 0.0f;
#pragma unroll 8
      for (int ch = 0; ch < 32; ++ch) {
        const float4 c = crow[ch];
        acc = fmaf(xs[w][4 * ch + 0], c.x, acc);
        acc = fmaf(xs[w][4 * ch + 1], c.y, acc);
        acc = fmaf(xs[w][4 * ch + 2], c.z, acc);
        acc = fmaf(xs[w][4 * ch + 3], c.w, acc);
      }
      const float dist = (sx - 2.0f * acc) + sumc2[code];
      pack = ((unsigned long long)__float_as_uint(dist) << 32) | (unsigned)code;
    }
#pragma unroll
    for (int s = 32; s >= 1; s >>= 1) {
      const unsigned long long o = __shfl_xor(pack, s, 64);
      pack = (o < pack) ? o : pack;
    }
    bestp = (pack < bestp) ? pack : bestp;
  }
  if (l == 0) best[tok] = bestp;
}

// Gather quantized_st + mse + sel_cos partials + idx + histogram.
__global__ __launch_bounds__(256) void k_gather(const float* __restrict__ lat,
                                                const float* __restrict__ cb,
                                                const float* __restrict__ sumx2,
                                                const float* __restrict__ sumc2,
                                                const unsigned long long* __restrict__ best,
                                                float* __restrict__ qout,
                                                float* __restrict__ idx_out,
                                                float* __restrict__ accum,
                                                int* __restrict__ cnt) {
  const int wave = threadIdx.x >> 6, lane = threadIdx.x & 63;
  __shared__ float sm[8];
  float msel = 0.0f, cosl = 0.0f;
  const int base = blockIdx.x * 64 + wave * 16;
  for (int it = 0; it < 16; ++it) {
    const int tok = base + it;
    const int code = (int)(best[tok] & 0xFFFFFFFFull);
    float2 l2 = *(const float2*)(lat + (size_t)tok * DIM + lane * 2);
    float2 c2 = *(const float2*)(cb + (size_t)code * DIM + lane * 2);
    const float o0 = l2.x + (c2.x - l2.x);
    const float o1 = l2.y + (c2.y - l2.y);
    *(float2*)(qout + (size_t)tok * DIM + lane * 2) = make_float2(o0, o1);
    const float e0 = l2.x - c2.x, e1 = l2.y - c2.y;
    msel += e0 * e0 + e1 * e1;
    float dt = l2.x * c2.x + l2.y * c2.y;
#pragma unroll
    for (int m = 32; m >= 1; m >>= 1) dt += __shfl_xor(dt, m, 64);
    if (lane == 0) {
      const float nx = fmaxf(sqrtf(sumx2[tok]), 1e-12f);
      const float nc = fmaxf(sqrtf(sumc2[code]), 1e-12f);
      cosl += dt / (nx * nc);
      idx_out[tok] = (float)code;
      atomicAdd(&cnt[code], 1);
    }
  }
#pragma unroll
  for (int m = 32; m >= 1; m >>= 1) msel += __shfl_xor(msel, m, 64);
  if (lane == 0) { sm[wave] = msel; sm[4 + wave] = cosl; }
  __syncthreads();
  if (threadIdx.x == 0) {
    atomicAdd(&accum[0], sm[0] + sm[1] + sm[2] + sm[3]);
    atomicAdd(&accum[1], sm[4] + sm[5] + sm[6] + sm[7]);
  }
}

// Codebook pairwise distances: 128x128 tiles, upper-triangular (x2 off-diag).
#define TILE 128
__global__ __launch_bounds__(256, 2) void k_pair(const float* __restrict__ cb,
                                                 const float* __restrict__ sumc2,
                                                 float* __restrict__ accum,
                                                 unsigned* __restrict__ minbits) {
  const int bj = blockIdx.y, bk = blockIdx.x;
  if (bj > bk) return;
  __shared__ __align__(16) unsigned char smem[66560 + 512];
  float (*Cj)[TILE] = (float (*)[TILE])smem;
  float (*Ck)[TILE] = (float (*)[TILE])(smem + 32768);
  float* qj = (float*)(smem + 65536);
  float* qk = (float*)(smem + 66048);

  const int t  = threadIdx.x;
  const int tx = t & 15, ty = t >> 4;
  const int r_stage = t & 127;
  const int h_stage = t >> 7;

  float acc[8][8];
#pragma unroll
  for (int a = 0; a < 8; ++a)
#pragma unroll
    for (int b = 0; b < 8; ++b) acc[a][b] = 0.0f;

  for (int dc = 0; dc < DIM; dc += 64) {
    __syncthreads();
    {
      const float* jsrc = cb + (size_t)(bj * TILE + r_stage) * DIM + dc + h_stage * 32;
#pragma unroll
      for (int p = 0; p < 8; ++p) {
        float4 v = *(const float4*)(jsrc + p * 4);
        const int d = h_stage * 32 + p * 4;
        Cj[d + 0][r_stage] = v.x; Cj[d + 1][r_stage] = v.y;
        Cj[d + 2][r_stage] = v.z; Cj[d + 3][r_stage] = v.w;
      }
      const float* ksrc = cb + (size_t)(bk * TILE + r_stage) * DIM + dc + h_stage * 32;
#pragma unroll
      for (int p = 0; p < 8; ++p) {
        float4 v = *(const float4*)(ksrc + p * 4);
        const int d = h_stage * 32 + p * 4;
        Ck[d + 0][r_stage] = v.x; Ck[d + 1][r_stage] = v.y;
        Ck[d + 2][r_stage] = v.z; Ck[d + 3][r_stage] = v.w;
      }
      if (dc == 0) {
        if (t < TILE) qj[t] = sumc2[bj * TILE + t];
        else          qk[t - TILE] = sumc2[bk * TILE + (t - TILE)];
      }
    }
    __syncthreads();

#pragma unroll 4
    for (int d = 0; d < 64; ++d) {
      float4 a0 = *(const float4*)&Cj[d][ty * 4];
      float4 a1 = *(const float4*)&Cj[d][64 + ty * 4];
      float4 b0 = *(const float4*)&Ck[d][tx * 4];
      float4 b1 = *(const float4*)&Ck[d][64 + tx * 4];
      const float aa[8] = {a0.x, a0.y, a0.z, a0.w, a1.x, a1.y, a1.z, a1.w};
      const float bb[8] = {b0.x, b0.y, b0.z, b0.w, b1.x, b1.y, b1.z, b1.w};
#pragma unroll
      for (int a = 0; a < 8; ++a)
#pragma unroll
        for (int b = 0; b < 8; ++b)
          acc[a][b] = fmaf(aa[a], bb[b], acc[a][b]);
    }
  }

  float lsum = 0.0f, lmin = INFINITY;
#pragma unroll
  for (int a = 0; a < 8; ++a) {
#pragma unroll
    for (int b = 0; b < 8; ++b) {
      const int jl = ty * 4 + (a & 3) + ((a >> 2) << 6);
      const int kl = tx * 4 + (b & 3) + ((b >> 2) << 6);
      const int j = bj * TILE + jl;
      const int k = bk * TILE + kl;
      const float d2 = (qj[jl] + qk[kl]) - 2.0f * acc[a][b];
      const float dd = sqrtf(fmaxf(d2, 0.0f));
      lsum += dd;
      if (j != k) lmin = fminf(lmin, dd);
    }
  }
  const float scale = (bj == bk) ? 1.0f : 2.0f;

  __syncthreads();
  float* reds = (float*)smem;
  reds[t] = lsum;
  __syncthreads();
  for (int s = 128; s >= 1; s >>= 1) {
    if (t < s) reds[t] += reds[t + s];
    __syncthreads();
  }
  if (t == 0) atomicAdd(&accum[2], reds[0] * scale);
  __syncthreads();
  reds[t] = lmin;
  __syncthreads();
  for (int s = 128; s >= 1; s >>= 1) {
    if (t < s) reds[t] = fminf(reds[t], reds[t + s]);
    __syncthreads();
  }
  if (t == 0) atomicMin(minbits, __float_as_uint(reds[0]));
}

__global__ __launch_bounds__(256) void k_final(const int* __restrict__ cnt,
                                               const float* __restrict__ accum,
                                               const unsigned* __restrict__ minbits,
                                               float* __restrict__ outs) {
  __shared__ float sh[256];
  const int t = threadIdx.x;
  float ent = 0.0f;
  for (int k = t; k < KCB; k += 256) {
    const float p = (float)cnt[k] * (1.0f / (float)NTOK);
    ent += p * logf(p + 1e-10f);
  }
  sh[t] = ent;
  __syncthreads();
  for (int s = 128; s >= 1; s >>= 1) {
    if (t < s) sh[t] += sh[t + s];
    __syncthreads();
  }
  if (t == 0) {
    const float mse = accum[0] * (1.0f / (float)(NTOK * DIM));
    outs[0] = 0.25f * mse;
    outs[1] = mse;
    outs[2] = expf(-sh[0]);
    outs[3] = accum[1] * (1.0f / (float)NTOK);
    outs[4] = accum[2] / ((float)KCB * (float)(KCB - 1));
    outs[5] = __uint_as_float(*minbits);
  }
}

extern "C" void kernel_launch(void* const* d_in, const int* in_sizes, int n_in,
                              void* d_out, int out_size, void* d_ws, size_t ws_size,
                              hipStream_t stream) {
  const float* lat = (const float*)d_in[0];
  const float* cb  = (const float*)d_in[1];

  float* out     = (float*)d_out;
  float* qout    = out;
  float* idx_out = out + (size_t)NTOK * DIM;
  float* outs    = idx_out + NTOK;

  float* W        = (float*)d_ws;
  float* accum    = W;
  unsigned* minb  = (unsigned*)(W + 3);
  float* sumx2    = W + 16;                        // NTOK
  float* sumc2    = sumx2 + NTOK;                  // KCB
  float* absum    = sumc2 + KCB;                   // NTOK
  int*   cnt      = (int*)(absum + NTOK);          // KCB
  unsigned long long* best = (unsigned long long*)(cnt + KCB);   // NTOK u64
  unsigned short* cbh    = (unsigned short*)(best + NTOK);       // KCB*DIM
  unsigned short* gmax16 = cbh + (size_t)KCB * DIM;              // NTOK*NG16

  hipLaunchKernelGGL(k_init, dim3(1), dim3(256), 0, stream, accum, minb, cnt);
  hipLaunchKernelGGL(k_convert, dim3(KCB * DIM / (256 * 8)), dim3(256), 0, stream, cb, cbh);
  hipLaunchKernelGGL(k_rownorm, dim3((NTOK + KCB) / 4), dim3(256), 0, stream,
                     lat, cb, sumx2, sumc2, absum);
  hipLaunchKernelGGL(k_approx, dim3(NTOK / 128, 8), dim3(256), 0, stream,
                     lat, cbh, gmax16);
  hipLaunchKernelGGL(k_resolve, dim3(NTOK / 4), dim3(256), 0, stream,
                     lat, cb, sumx2, sumc2, absum, gmax16, best);
  hipLaunchKernelGGL(k_gather, dim3(NTOK / 64), dim3(256), 0, stream,
                     lat, cb, sumx2, sumc2, best, qout, idx_out, accum, cnt);
  hipLaunchKernelGGL(k_pair, dim3(KCB / TILE, KCB / TILE), dim3(256), 0, stream,
                     cb, sumc2, accum, minb);
  hipLaunchKernelGGL(k_final, dim3(1), dim3(256), 0, stream, cnt, accum, minb, outs);
}

// Round 7
// 186.031 us; speedup vs baseline: 6.8034x; 1.1159x over previous
//
#include <hip/hip_runtime.h>
#include <hip/hip_fp16.h>
#include <math.h>

#define NTOK 16384
#define KCB  4096
#define DIM  128
#define NG16 (KCB / 16)     // 256 16-code groups

typedef short bf16x8 __attribute__((ext_vector_type(8)));
typedef float f32x4  __attribute__((ext_vector_type(4)));

// RNE float -> bf16 bits
static __device__ inline unsigned short rne_bf16(float f) {
  unsigned u = __float_as_uint(f);
  return (unsigned short)((u + 0x7FFFu + ((u >> 16) & 1u)) >> 16);
}

// ---------------------------------------------------------------------------
// ws layout (float offsets):
//   [0..2] accum: 0=mse_sum, 1=cos_sum, 2=pair_sum
//   [3]    minbits (unsigned, +inf init)
//   [16]        sumx2[NTOK]
//   +NTOK       sumc2[KCB]
//   +KCB        absum[NTOK]
//   +NTOK       cnt[KCB] (int)
//   +KCB        best[NTOK] (u64)
//   +2*NTOK     cbh[KCB*DIM] (ushort bf16 hi)
//   +KCB*DIM/2  gmax16[NTOK*NG16] (ushort fp16, row-major per token)
//   +...        cbl[KCB*DIM] (ushort bf16 lo residual)
// ---------------------------------------------------------------------------

__global__ __launch_bounds__(256) void k_init(float* __restrict__ accum,
                                              unsigned* __restrict__ minbits,
                                              int* __restrict__ cnt) {
  const int t = threadIdx.x;
  if (t < 3) accum[t] = 0.0f;
  if (t == 3) *minbits = 0x7F800000u;
  for (int k = t; k < KCB; k += 256) cnt[k] = 0;
}

// codebook fp32 -> bf16 hi + bf16 lo residual
__global__ __launch_bounds__(256) void k_convert(const float* __restrict__ cb,
                                                 unsigned short* __restrict__ cbh,
                                                 unsigned short* __restrict__ cbl) {
  const int base = (blockIdx.x * 256 + threadIdx.x) * 8;
  ushort4 h0, h1, l0, l1;
  float v[8];
  *(float4*)(v) = *(const float4*)(cb + base);
  *(float4*)(v + 4) = *(const float4*)(cb + base + 4);
  unsigned short h[8], lo[8];
#pragma unroll
  for (int i = 0; i < 8; ++i) {
    h[i] = rne_bf16(v[i]);
    const float hf = __uint_as_float((unsigned)h[i] << 16);
    lo[i] = rne_bf16(v[i] - hf);
  }
  h0.x = h[0]; h0.y = h[1]; h0.z = h[2]; h0.w = h[3];
  h1.x = h[4]; h1.y = h[5]; h1.z = h[6]; h1.w = h[7];
  l0.x = lo[0]; l0.y = lo[1]; l0.z = lo[2]; l0.w = lo[3];
  l1.x = lo[4]; l1.y = lo[5]; l1.z = lo[6]; l1.w = lo[7];
  *(ushort4*)(cbh + base) = h0;
  *(ushort4*)(cbh + base + 4) = h1;
  *(ushort4*)(cbl + base) = l0;
  *(ushort4*)(cbl + base + 4) = l1;
}

__global__ __launch_bounds__(256) void k_rownorm(const float* __restrict__ lat,
                                                 const float* __restrict__ cb,
                                                 float* __restrict__ sumx2,
                                                 float* __restrict__ sumc2,
                                                 float* __restrict__ absum) {
  const int row  = blockIdx.x * 4 + (threadIdx.x >> 6);
  const int lane = threadIdx.x & 63;
  const float* src = (row < NTOK) ? (lat + (size_t)row * DIM)
                                  : (cb + (size_t)(row - NTOK) * DIM);
  float2 v = *(const float2*)(src + lane * 2);
  double s  = (double)v.x * (double)v.x + (double)v.y * (double)v.y;
  double sa = fabs((double)v.x) + fabs((double)v.y);
#pragma unroll
  for (int m = 32; m >= 1; m >>= 1) {
    s  += __shfl_xor(s, m, 64);
    sa += __shfl_xor(sa, m, 64);
  }
  if (lane == 0) {
    if (row < NTOK) { sumx2[row] = (float)s; absum[row] = (float)sa; }
    else            sumc2[row - NTOK] = (float)s;
  }
}

// bf16 MFMA scan (values bit-identical to R4-R6).
__global__ __launch_bounds__(256) void k_approx(const float* __restrict__ lat,
                                                const unsigned short* __restrict__ cbh,
                                                unsigned short* __restrict__ gmax16) {
  __shared__ __align__(16) unsigned char smem[16384];
  const int t = threadIdx.x;
  const int w = t >> 6, l = t & 63;
  const int l15 = l & 15, lq = l >> 4;
  const int tokb = blockIdx.x * 128 + w * 32;
  const int ct0 = blockIdx.y * 8;

  bf16x8 bfr[2][4];
#pragma unroll
  for (int ctile = 0; ctile < 2; ++ctile) {
    const float* row = lat + (size_t)(tokb + ctile * 16 + l15) * DIM;
#pragma unroll
    for (int ks = 0; ks < 4; ++ks) {
      const int d0 = ks * 32 + lq * 4;
      float4 c0 = *(const float4*)(row + d0);
      float4 c1 = *(const float4*)(row + d0 + 16);
      union { ushort4 u4[2]; bf16x8 v; } cv;
      cv.u4[0].x = rne_bf16(c0.x); cv.u4[0].y = rne_bf16(c0.y);
      cv.u4[0].z = rne_bf16(c0.z); cv.u4[0].w = rne_bf16(c0.w);
      cv.u4[1].x = rne_bf16(c1.x); cv.u4[1].y = rne_bf16(c1.y);
      cv.u4[1].z = rne_bf16(c1.z); cv.u4[1].w = rne_bf16(c1.w);
      bfr[ctile][ks] = cv.v;
    }
  }

  for (int it = 0; it < 8; ++it) {
    const int ct = ct0 + it;
    __syncthreads();
    {
      const int r = t & 63, seg = t >> 6;
      const unsigned short* src = cbh + (size_t)(ct * 64 + r) * DIM + seg * 32;
      const int sw = (r & 7) << 4;
#pragma unroll
      for (int i = 0; i < 4; ++i) {
        uint4 v = *(const uint4*)(src + i * 8);
        *(uint4*)(smem + r * 256 + ((seg * 64 + i * 16) ^ sw)) = v;
      }
    }
    __syncthreads();

#pragma unroll
    for (int rt = 0; rt < 4; ++rt) {
      const int row = rt * 16 + l15;
      const int sw = (row & 7) << 4;
      bf16x8 afr[4];
#pragma unroll
      for (int ks = 0; ks < 4; ++ks) {
        const int off = ks * 64 + lq * 8;
        union { uint2 u2[2]; bf16x8 v; } cv;
        cv.u2[0] = *(const uint2*)(smem + row * 256 + (off ^ sw));
        cv.u2[1] = *(const uint2*)(smem + row * 256 + (((off + 32)) ^ sw));
        afr[ks] = cv.v;
      }
#pragma unroll
      for (int ctile = 0; ctile < 2; ++ctile) {
        f32x4 acc = {0.0f, 0.0f, 0.0f, 0.0f};
#pragma unroll
        for (int ks = 0; ks < 4; ++ks)
          acc = __builtin_amdgcn_mfma_f32_16x16x32_bf16(afr[ks], bfr[ctile][ks], acc, 0, 0, 0);
        float gm = fmaxf(fmaxf(acc[0], acc[1]), fmaxf(acc[2], acc[3]));
        gm = fmaxf(gm, __shfl_xor(gm, 16, 64));
        gm = fmaxf(gm, __shfl_xor(gm, 32, 64));
        if (lq == 0) {
          const int tok = tokb + ctile * 16 + l15;
          gmax16[(size_t)tok * NG16 + (ct * 4 + rt)] =
              __half_as_ushort(__float2half(gm));
        }
      }
    }
  }
}

// One wave per token (unchanged from R6).
__global__ __launch_bounds__(256) void k_resolve(const float* __restrict__ lat,
                                                 const float* __restrict__ cb,
                                                 const float* __restrict__ sumx2,
                                                 const float* __restrict__ sumc2,
                                                 const float* __restrict__ absum,
                                                 const unsigned short* __restrict__ gmax16,
                                                 unsigned long long* __restrict__ best) {
  __shared__ float xs[4][DIM];
  __shared__ unsigned char q[4][NG16];
  __shared__ int qn[4];
  const int w = threadIdx.x >> 6, l = threadIdx.x & 63;
  const int tok = blockIdx.x * 4 + w;

  if (l == 0) qn[w] = 0;
  {
    float2 xv = *(const float2*)(lat + (size_t)tok * DIM + l * 2);
    xs[w][l * 2] = xv.x; xs[w][l * 2 + 1] = xv.y;
  }
  const ushort4 hv = *(const ushort4*)(gmax16 + (size_t)tok * NG16 + l * 4);
  const float h0 = __half2float(__ushort_as_half(hv.x));
  const float h1 = __half2float(__ushort_as_half(hv.y));
  const float h2 = __half2float(__ushort_as_half(hv.z));
  const float h3 = __half2float(__ushort_as_half(hv.w));
  float m = fmaxf(fmaxf(h0, h1), fmaxf(h2, h3));
#pragma unroll
  for (int s = 32; s >= 1; s >>= 1) m = fmaxf(m, __shfl_xor(m, s, 64));
  const float thr = m - (absum[tok] * 3.8224e-6f + 6.0e-5f);

  if (h0 >= thr) { const int p = atomicAdd(&qn[w], 1); q[w][p] = (unsigned char)(l * 4 + 0); }
  if (h1 >= thr) { const int p = atomicAdd(&qn[w], 1); q[w][p] = (unsigned char)(l * 4 + 1); }
  if (h2 >= thr) { const int p = atomicAdd(&qn[w], 1); q[w][p] = (unsigned char)(l * 4 + 2); }
  if (h3 >= thr) { const int p = atomicAdd(&qn[w], 1); q[w][p] = (unsigned char)(l * 4 + 3); }
  __syncthreads();

  const int n = qn[w];
  const float sx = sumx2[tok];
  const int sub = l >> 4, cl = l & 15;
  unsigned long long bestp = ~0ull;

  for (int base = 0; base < n; base += 4) {
    unsigned long long pack = ~0ull;
    const int qi = base + sub;
    if (qi < n) {
      const int g = (int)q[w][qi];
      const int code = g * 16 + cl;
      const float4* crow = (const float4*)(cb + (size_t)code * DIM);
      float acc = 0.0f;
#pragma unroll 8
      for (int ch = 0; ch < 32; ++ch) {
        const float4 c = crow[ch];
        acc = fmaf(xs[w][4 * ch + 0], c.x, acc);
        acc = fmaf(xs[w][4 * ch + 1], c.y, acc);
        acc = fmaf(xs[w][4 * ch + 2], c.z, acc);
        acc = fmaf(xs[w][4 * ch + 3], c.w, acc);
      }
      const float dist = (sx - 2.0f * acc) + sumc2[code];
      pack = ((unsigned long long)__float_as_uint(dist) << 32) | (unsigned)code;
    }
#pragma unroll
    for (int s = 32; s >= 1; s >>= 1) {
      const unsigned long long o = __shfl_xor(pack, s, 64);
      pack = (o < pack) ? o : pack;
    }
    bestp = (pack < bestp) ? pack : bestp;
  }
  if (l == 0) best[tok] = bestp;
}

__global__ __launch_bounds__(256) void k_gather(const float* __restrict__ lat,
                                                const float* __restrict__ cb,
                                                const float* __restrict__ sumx2,
                                                const float* __restrict__ sumc2,
                                                const unsigned long long* __restrict__ best,
                                                float* __restrict__ qout,
                                                float* __restrict__ idx_out,
                                                float* __restrict__ accum,
                                                int* __restrict__ cnt) {
  const int wave = threadIdx.x >> 6, lane = threadIdx.x & 63;
  __shared__ float sm[8];
  float msel = 0.0f, cosl = 0.0f;
  const int base = blockIdx.x * 64 + wave * 16;
  for (int it = 0; it < 16; ++it) {
    const int tok = base + it;
    const int code = (int)(best[tok] & 0xFFFFFFFFull);
    float2 l2 = *(const float2*)(lat + (size_t)tok * DIM + lane * 2);
    float2 c2 = *(const float2*)(cb + (size_t)code * DIM + lane * 2);
    const float o0 = l2.x + (c2.x - l2.x);
    const float o1 = l2.y + (c2.y - l2.y);
    *(float2*)(qout + (size_t)tok * DIM + lane * 2) = make_float2(o0, o1);
    const float e0 = l2.x - c2.x, e1 = l2.y - c2.y;
    msel += e0 * e0 + e1 * e1;
    float dt = l2.x * c2.x + l2.y * c2.y;
#pragma unroll
    for (int m = 32; m >= 1; m >>= 1) dt += __shfl_xor(dt, m, 64);
    if (lane == 0) {
      const float nx = fmaxf(sqrtf(sumx2[tok]), 1e-12f);
      const float nc = fmaxf(sqrtf(sumc2[code]), 1e-12f);
      cosl += dt / (nx * nc);
      idx_out[tok] = (float)code;
      atomicAdd(&cnt[code], 1);
    }
  }
#pragma unroll
  for (int m = 32; m >= 1; m >>= 1) msel += __shfl_xor(msel, m, 64);
  if (lane == 0) { sm[wave] = msel; sm[4 + wave] = cosl; }
  __syncthreads();
  if (threadIdx.x == 0) {
    atomicAdd(&accum[0], sm[0] + sm[1] + sm[2] + sm[3]);
    atomicAdd(&accum[1], sm[4] + sm[5] + sm[6] + sm[7]);
  }
}

// Codebook pairwise via MFMA hi/lo split: dot = hh + hl + lh (err ~1e-10).
// Full 4096x4096 (matches reference's full-matrix sum incl. ~0 diagonal).
// Block: 4 waves x 32 j-codes; y-block = 4 k-tiles of 64 codes.
__global__ __launch_bounds__(256, 2) void k_pair_mfma(const unsigned short* __restrict__ cbh,
                                                      const unsigned short* __restrict__ cbl,
                                                      const float* __restrict__ sumc2,
                                                      float* __restrict__ accum,
                                                      unsigned* __restrict__ minbits) {
  __shared__ __align__(16) unsigned char smem[33792];  // hi 16K | lo 16K | qs 256B
  const int t = threadIdx.x;
  const int w = t >> 6, l = t & 63;
  const int l15 = l & 15, lq = l >> 4;
  const int jb = blockIdx.x * 128 + w * 32;
  const int kt0 = blockIdx.y * 4;
  float* qs = (float*)(smem + 32768);

  // B-frags: 2 ctiles x 4 ks, hi and lo, for j codes jb..jb+31
  bf16x8 bh[2][4], bl[2][4];
#pragma unroll
  for (int ct = 0; ct < 2; ++ct) {
    const unsigned short* rh = cbh + (size_t)(jb + ct * 16 + l15) * DIM;
    const unsigned short* rl = cbl + (size_t)(jb + ct * 16 + l15) * DIM;
#pragma unroll
    for (int ks = 0; ks < 4; ++ks) {
      const int d0 = ks * 32 + lq * 4;
      union { ushort4 u4[2]; bf16x8 v; } ch, cl2;
      ch.u4[0] = *(const ushort4*)(rh + d0);
      ch.u4[1] = *(const ushort4*)(rh + d0 + 16);
      cl2.u4[0] = *(const ushort4*)(rl + d0);
      cl2.u4[1] = *(const ushort4*)(rl + d0 + 16);
      bh[ct][ks] = ch.v;
      bl[ct][ks] = cl2.v;
    }
  }
  const float qj0 = sumc2[jb + l15];
  const float qj1 = sumc2[jb + 16 + l15];
  const int jg0 = jb + l15, jg1 = jb + 16 + l15;

  float lsum = 0.0f, lmin = INFINITY;

  for (int it = 0; it < 4; ++it) {
    const int kt = kt0 + it;       // 64-code k-tile
    __syncthreads();
    {  // stage hi+lo tiles (swizzled) + qs
      const int r = t & 63, seg = t >> 6;
      const int sw = (r & 7) << 4;
      const unsigned short* sh = cbh + (size_t)(kt * 64 + r) * DIM + seg * 32;
      const unsigned short* sl = cbl + (size_t)(kt * 64 + r) * DIM + seg * 32;
#pragma unroll
      for (int i = 0; i < 4; ++i) {
        uint4 vh = *(const uint4*)(sh + i * 8);
        uint4 vl = *(const uint4*)(sl + i * 8);
        *(uint4*)(smem + r * 256 + ((seg * 64 + i * 16) ^ sw)) = vh;
        *(uint4*)(smem + 16384 + r * 256 + ((seg * 64 + i * 16) ^ sw)) = vl;
      }
      if (t < 64) qs[t] = sumc2[kt * 64 + t];
    }
    __syncthreads();

#pragma unroll
    for (int rt = 0; rt < 4; ++rt) {
      const int row = rt * 16 + l15;
      const int sw = (row & 7) << 4;
      bf16x8 afh[4], afl[4];
#pragma unroll
      for (int ks = 0; ks < 4; ++ks) {
        const int off = ks * 64 + lq * 8;
        union { uint2 u2[2]; bf16x8 v; } cv;
        cv.u2[0] = *(const uint2*)(smem + row * 256 + (off ^ sw));
        cv.u2[1] = *(const uint2*)(smem + row * 256 + ((off + 32) ^ sw));
        afh[ks] = cv.v;
        union { uint2 u2[2]; bf16x8 v; } cw;
        cw.u2[0] = *(const uint2*)(smem + 16384 + row * 256 + (off ^ sw));
        cw.u2[1] = *(const uint2*)(smem + 16384 + row * 256 + ((off + 32) ^ sw));
        afl[ks] = cw.v;
      }
      f32x4 aA = {0.0f, 0.0f, 0.0f, 0.0f};
      f32x4 aB = {0.0f, 0.0f, 0.0f, 0.0f};
#pragma unroll
      for (int ks = 0; ks < 4; ++ks) {
        aA = __builtin_amdgcn_mfma_f32_16x16x32_bf16(afh[ks], bh[0][ks], aA, 0, 0, 0);
        aB = __builtin_amdgcn_mfma_f32_16x16x32_bf16(afh[ks], bh[1][ks], aB, 0, 0, 0);
      }
#pragma unroll
      for (int ks = 0; ks < 4; ++ks) {
        aA = __builtin_amdgcn_mfma_f32_16x16x32_bf16(afh[ks], bl[0][ks], aA, 0, 0, 0);
        aB = __builtin_amdgcn_mfma_f32_16x16x32_bf16(afh[ks], bl[1][ks], aB, 0, 0, 0);
      }
#pragma unroll
      for (int ks = 0; ks < 4; ++ks) {
        aA = __builtin_amdgcn_mfma_f32_16x16x32_bf16(afl[ks], bh[0][ks], aA, 0, 0, 0);
        aB = __builtin_amdgcn_mfma_f32_16x16x32_bf16(afl[ks], bh[1][ks], aB, 0, 0, 0);
      }
      // epilogue: C/D row=(lq*4+reg) -> k-code, col=l15 -> j-code [m89]
#pragma unroll
      for (int reg = 0; reg < 4; ++reg) {
        const int krl = rt * 16 + lq * 4 + reg;
        const int kg = kt * 64 + krl;
        const float qk = qs[krl];
        const float d2A = (qj0 + qk) - 2.0f * aA[reg];
        const float d2B = (qj1 + qk) - 2.0f * aB[reg];
        const float ddA = sqrtf(fmaxf(d2A, 0.0f));
        const float ddB = sqrtf(fmaxf(d2B, 0.0f));
        lsum += ddA + ddB;
        if (jg0 != kg) lmin = fminf(lmin, ddA);
        if (jg1 != kg) lmin = fminf(lmin, ddB);
      }
    }
  }

  __syncthreads();
  float* reds = (float*)smem;
  reds[t] = lsum;
  __syncthreads();
  for (int s = 128; s >= 1; s >>= 1) {
    if (t < s) reds[t] += reds[t + s];
    __syncthreads();
  }
  if (t == 0) atomicAdd(&accum[2], reds[0]);
  __syncthreads();
  reds[t] = lmin;
  __syncthreads();
  for (int s = 128; s >= 1; s >>= 1) {
    if (t < s) reds[t] = fminf(reds[t], reds[t + s]);
    __syncthreads();
  }
  if (t == 0) atomicMin(minbits, __float_as_uint(reds[0]));
}

__global__ __launch_bounds__(256) void k_final(const int* __restrict__ cnt,
                                               const float* __restrict__ accum,
                                               const unsigned* __restrict__ minbits,
                                               float* __restrict__ outs) {
  __shared__ float sh[256];
  const int t = threadIdx.x;
  float ent = 0.0f;
  for (int k = t; k < KCB; k += 256) {
    const float p = (float)cnt[k] * (1.0f / (float)NTOK);
    ent += p * logf(p + 1e-10f);
  }
  sh[t] = ent;
  __syncthreads();
  for (int s = 128; s >= 1; s >>= 1) {
    if (t < s) sh[t] += sh[t + s];
    __syncthreads();
  }
  if (t == 0) {
    const float mse = accum[0] * (1.0f / (float)(NTOK * DIM));
    outs[0] = 0.25f * mse;
    outs[1] = mse;
    outs[2] = expf(-sh[0]);
    outs[3] = accum[1] * (1.0f / (float)NTOK);
    outs[4] = accum[2] / ((float)KCB * (float)(KCB - 1));
    outs[5] = __uint_as_float(*minbits);
  }
}

extern "C" void kernel_launch(void* const* d_in, const int* in_sizes, int n_in,
                              void* d_out, int out_size, void* d_ws, size_t ws_size,
                              hipStream_t stream) {
  const float* lat = (const float*)d_in[0];
  const float* cb  = (const float*)d_in[1];

  float* out     = (float*)d_out;
  float* qout    = out;
  float* idx_out = out + (size_t)NTOK * DIM;
  float* outs    = idx_out + NTOK;

  float* W        = (float*)d_ws;
  float* accum    = W;
  unsigned* minb  = (unsigned*)(W + 3);
  float* sumx2    = W + 16;                        // NTOK
  float* sumc2    = sumx2 + NTOK;                  // KCB
  float* absum    = sumc2 + KCB;                   // NTOK
  int*   cnt      = (int*)(absum + NTOK);          // KCB
  unsigned long long* best = (unsigned long long*)(cnt + KCB);   // NTOK u64
  unsigned short* cbh    = (unsigned short*)(best + NTOK);       // KCB*DIM
  unsigned short* gmax16 = cbh + (size_t)KCB * DIM;              // NTOK*NG16
  unsigned short* cbl    = gmax16 + (size_t)NTOK * NG16;         // KCB*DIM

  hipLaunchKernelGGL(k_init, dim3(1), dim3(256), 0, stream, accum, minb, cnt);
  hipLaunchKernelGGL(k_convert, dim3(KCB * DIM / (256 * 8)), dim3(256), 0, stream,
                     cb, cbh, cbl);
  hipLaunchKernelGGL(k_rownorm, dim3((NTOK + KCB) / 4), dim3(256), 0, stream,
                     lat, cb, sumx2, sumc2, absum);
  hipLaunchKernelGGL(k_approx, dim3(NTOK / 128, 8), dim3(256), 0, stream,
                     lat, cbh, gmax16);
  hipLaunchKernelGGL(k_resolve, dim3(NTOK / 4), dim3(256), 0, stream,
                     lat, cb, sumx2, sumc2, absum, gmax16, best);
  hipLaunchKernelGGL(k_gather, dim3(NTOK / 64), dim3(256), 0, stream,
                     lat, cb, sumx2, sumc2, best, qout, idx_out, accum, cnt);
  hipLaunchKernelGGL(k_pair_mfma, dim3(KCB / 128, KCB / 256), dim3(256), 0, stream,
                     cbh, cbl, sumc2, accum, minb);
  hipLaunchKernelGGL(k_final, dim3(1), dim3(256), 0, stream, cnt, accum, minb, outs);
}

// Round 8
// 181.717 us; speedup vs baseline: 6.9648x; 1.0237x over previous
//
#include <hip/hip_runtime.h>
#include <hip/hip_fp16.h>
#include <math.h>

#define NTOK 16384
#define KCB  4096
#define DIM  128
#define NG16 (KCB / 16)     // 256 16-code groups

typedef short bf16x8 __attribute__((ext_vector_type(8)));
typedef float f32x4  __attribute__((ext_vector_type(4)));

// RNE float -> bf16 bits
static __device__ inline unsigned short rne_bf16(float f) {
  unsigned u = __float_as_uint(f);
  return (unsigned short)((u + 0x7FFFu + ((u >> 16) & 1u)) >> 16);
}

// ---------------------------------------------------------------------------
// ws layout (float offsets):
//   [0..2] accum: 2=pair_sum (0,1 unused now)
//   [3]    minbits (unsigned, +inf init)
//   [16]        sumx2[NTOK]
//   +NTOK       sumc2[KCB]
//   +KCB        absum[NTOK]
//   +NTOK       cnt[KCB] (int)
//   +KCB        msum[NTOK]
//   +NTOK       csum[NTOK]
//   +NTOK       cbh[KCB*DIM] (ushort bf16 hi)
//   +KCB*DIM/2  gmax16[NTOK*NG16] (ushort fp16, row-major per token)
//   +...        cbl[KCB*DIM] (ushort bf16 lo residual)
// ---------------------------------------------------------------------------

__global__ __launch_bounds__(256) void k_init(float* __restrict__ accum,
                                              unsigned* __restrict__ minbits,
                                              int* __restrict__ cnt) {
  const int t = threadIdx.x;
  if (t < 3) accum[t] = 0.0f;
  if (t == 3) *minbits = 0x7F800000u;
  for (int k = t; k < KCB; k += 256) cnt[k] = 0;
}

// codebook fp32 -> bf16 hi + bf16 lo residual
__global__ __launch_bounds__(256) void k_convert(const float* __restrict__ cb,
                                                 unsigned short* __restrict__ cbh,
                                                 unsigned short* __restrict__ cbl) {
  const int base = (blockIdx.x * 256 + threadIdx.x) * 8;
  ushort4 h0, h1, l0, l1;
  float v[8];
  *(float4*)(v) = *(const float4*)(cb + base);
  *(float4*)(v + 4) = *(const float4*)(cb + base + 4);
  unsigned short h[8], lo[8];
#pragma unroll
  for (int i = 0; i < 8; ++i) {
    h[i] = rne_bf16(v[i]);
    const float hf = __uint_as_float((unsigned)h[i] << 16);
    lo[i] = rne_bf16(v[i] - hf);
  }
  h0.x = h[0]; h0.y = h[1]; h0.z = h[2]; h0.w = h[3];
  h1.x = h[4]; h1.y = h[5]; h1.z = h[6]; h1.w = h[7];
  l0.x = lo[0]; l0.y = lo[1]; l0.z = lo[2]; l0.w = lo[3];
  l1.x = lo[4]; l1.y = lo[5]; l1.z = lo[6]; l1.w = lo[7];
  *(ushort4*)(cbh + base) = h0;
  *(ushort4*)(cbh + base + 4) = h1;
  *(ushort4*)(cbl + base) = l0;
  *(ushort4*)(cbl + base + 4) = l1;
}

__global__ __launch_bounds__(256) void k_rownorm(const float* __restrict__ lat,
                                                 const float* __restrict__ cb,
                                                 float* __restrict__ sumx2,
                                                 float* __restrict__ sumc2,
                                                 float* __restrict__ absum) {
  const int row  = blockIdx.x * 4 + (threadIdx.x >> 6);
  const int lane = threadIdx.x & 63;
  const float* src = (row < NTOK) ? (lat + (size_t)row * DIM)
                                  : (cb + (size_t)(row - NTOK) * DIM);
  float2 v = *(const float2*)(src + lane * 2);
  double s  = (double)v.x * (double)v.x + (double)v.y * (double)v.y;
  double sa = fabs((double)v.x) + fabs((double)v.y);
#pragma unroll
  for (int m = 32; m >= 1; m >>= 1) {
    s  += __shfl_xor(s, m, 64);
    sa += __shfl_xor(sa, m, 64);
  }
  if (lane == 0) {
    if (row < NTOK) { sumx2[row] = (float)s; absum[row] = (float)sa; }
    else            sumc2[row - NTOK] = (float)s;
  }
}

// bf16 MFMA scan (values bit-identical to R4-R7).
__global__ __launch_bounds__(256) void k_approx(const float* __restrict__ lat,
                                                const unsigned short* __restrict__ cbh,
                                                unsigned short* __restrict__ gmax16) {
  __shared__ __align__(16) unsigned char smem[16384];
  const int t = threadIdx.x;
  const int w = t >> 6, l = t & 63;
  const int l15 = l & 15, lq = l >> 4;
  const int tokb = blockIdx.x * 128 + w * 32;
  const int ct0 = blockIdx.y * 8;

  bf16x8 bfr[2][4];
#pragma unroll
  for (int ctile = 0; ctile < 2; ++ctile) {
    const float* row = lat + (size_t)(tokb + ctile * 16 + l15) * DIM;
#pragma unroll
    for (int ks = 0; ks < 4; ++ks) {
      const int d0 = ks * 32 + lq * 4;
      float4 c0 = *(const float4*)(row + d0);
      float4 c1 = *(const float4*)(row + d0 + 16);
      union { ushort4 u4[2]; bf16x8 v; } cv;
      cv.u4[0].x = rne_bf16(c0.x); cv.u4[0].y = rne_bf16(c0.y);
      cv.u4[0].z = rne_bf16(c0.z); cv.u4[0].w = rne_bf16(c0.w);
      cv.u4[1].x = rne_bf16(c1.x); cv.u4[1].y = rne_bf16(c1.y);
      cv.u4[1].z = rne_bf16(c1.z); cv.u4[1].w = rne_bf16(c1.w);
      bfr[ctile][ks] = cv.v;
    }
  }

  for (int it = 0; it < 8; ++it) {
    const int ct = ct0 + it;
    __syncthreads();
    {
      const int r = t & 63, seg = t >> 6;
      const unsigned short* src = cbh + (size_t)(ct * 64 + r) * DIM + seg * 32;
      const int sw = (r & 7) << 4;
#pragma unroll
      for (int i = 0; i < 4; ++i) {
        uint4 v = *(const uint4*)(src + i * 8);
        *(uint4*)(smem + r * 256 + ((seg * 64 + i * 16) ^ sw)) = v;
      }
    }
    __syncthreads();

#pragma unroll
    for (int rt = 0; rt < 4; ++rt) {
      const int row = rt * 16 + l15;
      const int sw = (row & 7) << 4;
      bf16x8 afr[4];
#pragma unroll
      for (int ks = 0; ks < 4; ++ks) {
        const int off = ks * 64 + lq * 8;
        union { uint2 u2[2]; bf16x8 v; } cv;
        cv.u2[0] = *(const uint2*)(smem + row * 256 + (off ^ sw));
        cv.u2[1] = *(const uint2*)(smem + row * 256 + (((off + 32)) ^ sw));
        afr[ks] = cv.v;
      }
#pragma unroll
      for (int ctile = 0; ctile < 2; ++ctile) {
        f32x4 acc = {0.0f, 0.0f, 0.0f, 0.0f};
#pragma unroll
        for (int ks = 0; ks < 4; ++ks)
          acc = __builtin_amdgcn_mfma_f32_16x16x32_bf16(afr[ks], bfr[ctile][ks], acc, 0, 0, 0);
        float gm = fmaxf(fmaxf(acc[0], acc[1]), fmaxf(acc[2], acc[3]));
        gm = fmaxf(gm, __shfl_xor(gm, 16, 64));
        gm = fmaxf(gm, __shfl_xor(gm, 32, 64));
        if (lq == 0) {
          const int tok = tokb + ctile * 16 + l15;
          gmax16[(size_t)tok * NG16 + (ct * 4 + rt)] =
              __half_as_ushort(__float2half(gm));
        }
      }
    }
  }
}

// Fused resolve+gather. One wave per token, waves independent (no barriers).
// Candidate set bit-identical to R5-R7 (same gmax16 values, same thr formula);
// exact per-code chain bit-identical (same values/op order, float4 LDS reads).
// Ballot-compaction queue (no atomics). After winner: inline gather.
__global__ __launch_bounds__(256) void k_resolve(const float* __restrict__ lat,
                                                 const float* __restrict__ cb,
                                                 const float* __restrict__ sumx2,
                                                 const float* __restrict__ sumc2,
                                                 const float* __restrict__ absum,
                                                 const unsigned short* __restrict__ gmax16,
                                                 float* __restrict__ qout,
                                                 float* __restrict__ idx_out,
                                                 float* __restrict__ msum,
                                                 float* __restrict__ csum,
                                                 int* __restrict__ cnt) {
  __shared__ __align__(16) float xs[4][DIM];
  __shared__ unsigned char q[4][NG16];
  const int w = threadIdx.x >> 6, l = threadIdx.x & 63;
  const int tok = blockIdx.x * 4 + w;

  // independent loads up front
  const float2 xv = *(const float2*)(lat + (size_t)tok * DIM + l * 2);
  const ushort4 hv = *(const ushort4*)(gmax16 + (size_t)tok * NG16 + l * 4);
  const float sx = sumx2[tok];
  const float ab = absum[tok];
  *(float2*)(&xs[w][l * 2]) = xv;

  const float h0 = __half2float(__ushort_as_half(hv.x));
  const float h1 = __half2float(__ushort_as_half(hv.y));
  const float h2 = __half2float(__ushort_as_half(hv.z));
  const float h3 = __half2float(__ushort_as_half(hv.w));
  float m = fmaxf(fmaxf(h0, h1), fmaxf(h2, h3));
#pragma unroll
  for (int s = 32; s >= 1; s >>= 1) m = fmaxf(m, __shfl_xor(m, s, 64));
  const float thr = m - (ab * 3.8224e-6f + 6.0e-5f);

  // ballot compaction (order within queue irrelevant: min is commutative,
  // ties broken by packed idx)
  const unsigned long long lt = (l == 63) ? 0x7FFFFFFFFFFFFFFFull
                                          : ((1ull << l) - 1ull) | (1ull << l) ;
  // lt = mask of lanes strictly below l:
  const unsigned long long ltm = (1ull << l) - 1ull;
  const unsigned long long b0 = __ballot(h0 >= thr);
  const unsigned long long b1 = __ballot(h1 >= thr);
  const unsigned long long b2 = __ballot(h2 >= thr);
  const unsigned long long b3 = __ballot(h3 >= thr);
  const int n0 = __popcll(b0), n1 = __popcll(b1), n2 = __popcll(b2);
  if (h0 >= thr) q[w][__popcll(b0 & ltm)] = (unsigned char)(l * 4 + 0);
  if (h1 >= thr) q[w][n0 + __popcll(b1 & ltm)] = (unsigned char)(l * 4 + 1);
  if (h2 >= thr) q[w][n0 + n1 + __popcll(b2 & ltm)] = (unsigned char)(l * 4 + 2);
  if (h3 >= thr) q[w][n0 + n1 + n2 + __popcll(b3 & ltm)] = (unsigned char)(l * 4 + 3);
  const int n = n0 + n1 + n2 + __popcll(b3);
  (void)lt;

  const int sub = l >> 4, cl = l & 15;
  unsigned long long bestp = ~0ull;
  const float4* xr4 = (const float4*)xs[w];

  for (int base = 0; base < n; base += 4) {
    unsigned long long pack = ~0ull;
    const int qi = base + sub;
    if (qi < n) {
      const int g = (int)q[w][qi];
      const int code = g * 16 + cl;
      const float4* crow = (const float4*)(cb + (size_t)code * DIM);
      float acc = 0.0f;
#pragma unroll 8
      for (int ch = 0; ch < 32; ++ch) {
        const float4 c = crow[ch];
        const float4 x = xr4[ch];
        acc = fmaf(x.x, c.x, acc); acc = fmaf(x.y, c.y, acc);
        acc = fmaf(x.z, c.z, acc); acc = fmaf(x.w, c.w, acc);
      }
      const float dist = (sx - 2.0f * acc) + sumc2[code];
      pack = ((unsigned long long)__float_as_uint(dist) << 32) | (unsigned)code;
    }
#pragma unroll
    for (int s = 32; s >= 1; s >>= 1) {
      const unsigned long long o = __shfl_xor(pack, s, 64);
      pack = (o < pack) ? o : pack;
    }
    bestp = (pack < bestp) ? pack : bestp;
  }

  // ---- inline gather ----
  const int code = (int)(bestp & 0xFFFFFFFFull);
  const float2 c2 = *(const float2*)(cb + (size_t)code * DIM + l * 2);
  const float o0 = xv.x + (c2.x - xv.x);
  const float o1 = xv.y + (c2.y - xv.y);
  *(float2*)(qout + (size_t)tok * DIM + l * 2) = make_float2(o0, o1);
  const float e0 = xv.x - c2.x, e1 = xv.y - c2.y;
  float msel = e0 * e0 + e1 * e1;
  float dt = xv.x * c2.x + xv.y * c2.y;
#pragma unroll
  for (int s = 32; s >= 1; s >>= 1) {
    msel += __shfl_xor(msel, s, 64);
    dt += __shfl_xor(dt, s, 64);
  }
  if (l == 0) {
    const float nx = fmaxf(sqrtf(sx), 1e-12f);
    const float nc = fmaxf(sqrtf(sumc2[code]), 1e-12f);
    msum[tok] = msel;
    csum[tok] = dt / (nx * nc);
    idx_out[tok] = (float)code;
    atomicAdd(&cnt[code], 1);
  }
}

// Codebook pairwise via MFMA hi/lo split (unchanged from R7).
__global__ __launch_bounds__(256, 2) void k_pair_mfma(const unsigned short* __restrict__ cbh,
                                                      const unsigned short* __restrict__ cbl,
                                                      const float* __restrict__ sumc2,
                                                      float* __restrict__ accum,
                                                      unsigned* __restrict__ minbits) {
  __shared__ __align__(16) unsigned char smem[33792];
  const int t = threadIdx.x;
  const int w = t >> 6, l = t & 63;
  const int l15 = l & 15, lq = l >> 4;
  const int jb = blockIdx.x * 128 + w * 32;
  const int kt0 = blockIdx.y * 4;
  float* qs = (float*)(smem + 32768);

  bf16x8 bh[2][4], bl[2][4];
#pragma unroll
  for (int ct = 0; ct < 2; ++ct) {
    const unsigned short* rh = cbh + (size_t)(jb + ct * 16 + l15) * DIM;
    const unsigned short* rl = cbl + (size_t)(jb + ct * 16 + l15) * DIM;
#pragma unroll
    for (int ks = 0; ks < 4; ++ks) {
      const int d0 = ks * 32 + lq * 4;
      union { ushort4 u4[2]; bf16x8 v; } ch, cl2;
      ch.u4[0] = *(const ushort4*)(rh + d0);
      ch.u4[1] = *(const ushort4*)(rh + d0 + 16);
      cl2.u4[0] = *(const ushort4*)(rl + d0);
      cl2.u4[1] = *(const ushort4*)(rl + d0 + 16);
      bh[ct][ks] = ch.v;
      bl[ct][ks] = cl2.v;
    }
  }
  const float qj0 = sumc2[jb + l15];
  const float qj1 = sumc2[jb + 16 + l15];
  const int jg0 = jb + l15, jg1 = jb + 16 + l15;

  float lsum = 0.0f, lmin = INFINITY;

  for (int it = 0; it < 4; ++it) {
    const int kt = kt0 + it;
    __syncthreads();
    {
      const int r = t & 63, seg = t >> 6;
      const int sw = (r & 7) << 4;
      const unsigned short* sh = cbh + (size_t)(kt * 64 + r) * DIM + seg * 32;
      const unsigned short* sl = cbl + (size_t)(kt * 64 + r) * DIM + seg * 32;
#pragma unroll
      for (int i = 0; i < 4; ++i) {
        uint4 vh = *(const uint4*)(sh + i * 8);
        uint4 vl = *(const uint4*)(sl + i * 8);
        *(uint4*)(smem + r * 256 + ((seg * 64 + i * 16) ^ sw)) = vh;
        *(uint4*)(smem + 16384 + r * 256 + ((seg * 64 + i * 16) ^ sw)) = vl;
      }
      if (t < 64) qs[t] = sumc2[kt * 64 + t];
    }
    __syncthreads();

#pragma unroll
    for (int rt = 0; rt < 4; ++rt) {
      const int row = rt * 16 + l15;
      const int sw = (row & 7) << 4;
      bf16x8 afh[4], afl[4];
#pragma unroll
      for (int ks = 0; ks < 4; ++ks) {
        const int off = ks * 64 + lq * 8;
        union { uint2 u2[2]; bf16x8 v; } cv;
        cv.u2[0] = *(const uint2*)(smem + row * 256 + (off ^ sw));
        cv.u2[1] = *(const uint2*)(smem + row * 256 + ((off + 32) ^ sw));
        afh[ks] = cv.v;
        union { uint2 u2[2]; bf16x8 v; } cw;
        cw.u2[0] = *(const uint2*)(smem + 16384 + row * 256 + (off ^ sw));
        cw.u2[1] = *(const uint2*)(smem + 16384 + row * 256 + ((off + 32) ^ sw));
        afl[ks] = cw.v;
      }
      f32x4 aA = {0.0f, 0.0f, 0.0f, 0.0f};
      f32x4 aB = {0.0f, 0.0f, 0.0f, 0.0f};
#pragma unroll
      for (int ks = 0; ks < 4; ++ks) {
        aA = __builtin_amdgcn_mfma_f32_16x16x32_bf16(afh[ks], bh[0][ks], aA, 0, 0, 0);
        aB = __builtin_amdgcn_mfma_f32_16x16x32_bf16(afh[ks], bh[1][ks], aB, 0, 0, 0);
      }
#pragma unroll
      for (int ks = 0; ks < 4; ++ks) {
        aA = __builtin_amdgcn_mfma_f32_16x16x32_bf16(afh[ks], bl[0][ks], aA, 0, 0, 0);
        aB = __builtin_amdgcn_mfma_f32_16x16x32_bf16(afh[ks], bl[1][ks], aB, 0, 0, 0);
      }
#pragma unroll
      for (int ks = 0; ks < 4; ++ks) {
        aA = __builtin_amdgcn_mfma_f32_16x16x32_bf16(afl[ks], bh[0][ks], aA, 0, 0, 0);
        aB = __builtin_amdgcn_mfma_f32_16x16x32_bf16(afl[ks], bh[1][ks], aB, 0, 0, 0);
      }
#pragma unroll
      for (int reg = 0; reg < 4; ++reg) {
        const int krl = rt * 16 + lq * 4 + reg;
        const int kg = kt * 64 + krl;
        const float qk = qs[krl];
        const float d2A = (qj0 + qk) - 2.0f * aA[reg];
        const float d2B = (qj1 + qk) - 2.0f * aB[reg];
        const float ddA = sqrtf(fmaxf(d2A, 0.0f));
        const float ddB = sqrtf(fmaxf(d2B, 0.0f));
        lsum += ddA + ddB;
        if (jg0 != kg) lmin = fminf(lmin, ddA);
        if (jg1 != kg) lmin = fminf(lmin, ddB);
      }
    }
  }

  __syncthreads();
  float* reds = (float*)smem;
  reds[t] = lsum;
  __syncthreads();
  for (int s = 128; s >= 1; s >>= 1) {
    if (t < s) reds[t] += reds[t + s];
    __syncthreads();
  }
  if (t == 0) atomicAdd(&accum[2], reds[0]);
  __syncthreads();
  reds[t] = lmin;
  __syncthreads();
  for (int s = 128; s >= 1; s >>= 1) {
    if (t < s) reds[t] = fminf(reds[t], reds[t + s]);
    __syncthreads();
  }
  if (t == 0) atomicMin(minbits, __float_as_uint(reds[0]));
}

__global__ __launch_bounds__(256) void k_final(const int* __restrict__ cnt,
                                               const float* __restrict__ accum,
                                               const unsigned* __restrict__ minbits,
                                               const float* __restrict__ msum,
                                               const float* __restrict__ csum,
                                               float* __restrict__ outs) {
  __shared__ float sh[256];
  __shared__ float sh2[256];
  const int t = threadIdx.x;
  float ent = 0.0f;
  for (int k = t; k < KCB; k += 256) {
    const float p = (float)cnt[k] * (1.0f / (float)NTOK);
    ent += p * logf(p + 1e-10f);
  }
  float ms = 0.0f, cs = 0.0f;
  for (int i = t; i < NTOK; i += 256) { ms += msum[i]; cs += csum[i]; }
  sh[t] = ent;
  sh2[t] = ms;
  __syncthreads();
  for (int s = 128; s >= 1; s >>= 1) {
    if (t < s) { sh[t] += sh[t + s]; sh2[t] += sh2[t + s]; }
    __syncthreads();
  }
  const float ent_tot = sh[0];
  const float ms_tot = sh2[0];
  __syncthreads();
  sh[t] = cs;
  __syncthreads();
  for (int s = 128; s >= 1; s >>= 1) {
    if (t < s) sh[t] += sh[t + s];
    __syncthreads();
  }
  if (t == 0) {
    const float mse = ms_tot * (1.0f / (float)(NTOK * DIM));
    outs[0] = 0.25f * mse;
    outs[1] = mse;
    outs[2] = expf(-ent_tot);
    outs[3] = sh[0] * (1.0f / (float)NTOK);
    outs[4] = accum[2] / ((float)KCB * (float)(KCB - 1));
    outs[5] = __uint_as_float(*minbits);
  }
}

extern "C" void kernel_launch(void* const* d_in, const int* in_sizes, int n_in,
                              void* d_out, int out_size, void* d_ws, size_t ws_size,
                              hipStream_t stream) {
  const float* lat = (const float*)d_in[0];
  const float* cb  = (const float*)d_in[1];

  float* out     = (float*)d_out;
  float* qout    = out;
  float* idx_out = out + (size_t)NTOK * DIM;
  float* outs    = idx_out + NTOK;

  float* W        = (float*)d_ws;
  float* accum    = W;
  unsigned* minb  = (unsigned*)(W + 3);
  float* sumx2    = W + 16;                        // NTOK
  float* sumc2    = sumx2 + NTOK;                  // KCB
  float* absum    = sumc2 + KCB;                   // NTOK
  int*   cnt      = (int*)(absum + NTOK);          // KCB
  float* msum     = (float*)(cnt + KCB);           // NTOK
  float* csum     = msum + NTOK;                   // NTOK
  unsigned short* cbh    = (unsigned short*)(csum + NTOK);       // KCB*DIM
  unsigned short* gmax16 = cbh + (size_t)KCB * DIM;              // NTOK*NG16
  unsigned short* cbl    = gmax16 + (size_t)NTOK * NG16;         // KCB*DIM

  hipLaunchKernelGGL(k_init, dim3(1), dim3(256), 0, stream, accum, minb, cnt);
  hipLaunchKernelGGL(k_convert, dim3(KCB * DIM / (256 * 8)), dim3(256), 0, stream,
                     cb, cbh, cbl);
  hipLaunchKernelGGL(k_rownorm, dim3((NTOK + KCB) / 4), dim3(256), 0, stream,
                     lat, cb, sumx2, sumc2, absum);
  hipLaunchKernelGGL(k_approx, dim3(NTOK / 128, 8), dim3(256), 0, stream,
                     lat, cbh, gmax16);
  hipLaunchKernelGGL(k_resolve, dim3(NTOK / 4), dim3(256), 0, stream,
                     lat, cb, sumx2, sumc2, absum, gmax16,
                     qout, idx_out, msum, csum, cnt);
  hipLaunchKernelGGL(k_pair_mfma, dim3(KCB / 128, KCB / 256), dim3(256), 0, stream,
                     cbh, cbl, sumc2, accum, minb);
  hipLaunchKernelGGL(k_final, dim3(1), dim3(256), 0, stream, cnt, accum, minb,
                     msum, csum, outs);
}

// Round 9
// 167.761 us; speedup vs baseline: 7.5442x; 1.0832x over previous
//
#include <hip/hip_runtime.h>
#include <hip/hip_fp16.h>
#include <math.h>

#define NTOK 16384
#define KCB  4096
#define DIM  128
#define NG8  (KCB / 8)      // 512 8-code groups

typedef short bf16x8 __attribute__((ext_vector_type(8)));
typedef float f32x4  __attribute__((ext_vector_type(4)));

// RNE float -> bf16 bits
static __device__ inline unsigned short rne_bf16(float f) {
  unsigned u = __float_as_uint(f);
  return (unsigned short)((u + 0x7FFFu + ((u >> 16) & 1u)) >> 16);
}

// ---------------------------------------------------------------------------
// ws layout (float offsets from W):
//   [0]          sumx2[NTOK]
//   +NTOK        sumc2[KCB]
//   +KCB         absum[NTOK]
//   +NTOK        cnt[KCB] (int)
//   +KCB         msum[NTOK]
//   +NTOK        csum[NTOK]
//   +NTOK        pairsum[4096]
//   +4096        pairmin[4096]
//   +4096        cbh[KCB*DIM] (ushort bf16 hi)          = 1 MB
//   +KCB*DIM/2   gmax8[NTOK*NG8] (ushort fp16, row-major per token) = 16.8 MB
// ---------------------------------------------------------------------------

__global__ __launch_bounds__(256) void k_init(int* __restrict__ cnt) {
  const int t = threadIdx.x;
  for (int k = t; k < KCB; k += 256) cnt[k] = 0;
}

// codebook fp32 -> bf16 hi
__global__ __launch_bounds__(256) void k_convert(const float* __restrict__ cb,
                                                 unsigned short* __restrict__ cbh) {
  const int base = (blockIdx.x * 256 + threadIdx.x) * 8;
  float4 v0 = *(const float4*)(cb + base);
  float4 v1 = *(const float4*)(cb + base + 4);
  ushort4 o0, o1;
  o0.x = rne_bf16(v0.x); o0.y = rne_bf16(v0.y); o0.z = rne_bf16(v0.z); o0.w = rne_bf16(v0.w);
  o1.x = rne_bf16(v1.x); o1.y = rne_bf16(v1.y); o1.z = rne_bf16(v1.z); o1.w = rne_bf16(v1.w);
  *(ushort4*)(cbh + base) = o0;
  *(ushort4*)(cbh + base + 4) = o1;
}

__global__ __launch_bounds__(256) void k_rownorm(const float* __restrict__ lat,
                                                 const float* __restrict__ cb,
                                                 float* __restrict__ sumx2,
                                                 float* __restrict__ sumc2,
                                                 float* __restrict__ absum) {
  const int row  = blockIdx.x * 4 + (threadIdx.x >> 6);
  const int lane = threadIdx.x & 63;
  const float* src = (row < NTOK) ? (lat + (size_t)row * DIM)
                                  : (cb + (size_t)(row - NTOK) * DIM);
  float2 v = *(const float2*)(src + lane * 2);
  double s  = (double)v.x * (double)v.x + (double)v.y * (double)v.y;
  double sa = fabs((double)v.x) + fabs((double)v.y);
#pragma unroll
  for (int m = 32; m >= 1; m >>= 1) {
    s  += __shfl_xor(s, m, 64);
    sa += __shfl_xor(sa, m, 64);
  }
  if (lane == 0) {
    if (row < NTOK) { sumx2[row] = (float)s; absum[row] = (float)sa; }
    else            sumc2[row - NTOK] = (float)s;
  }
}

// bf16 MFMA scan. MFMA accs bit-identical to R4-R8; output granularity 8 codes:
// h8 = fp16(max over 8 accs) — fp16-RNE is monotone so global max m1 is
// unchanged and the per-group exclusion certificate holds at any granularity.
__global__ __launch_bounds__(256) void k_approx(const float* __restrict__ lat,
                                                const unsigned short* __restrict__ cbh,
                                                unsigned short* __restrict__ gmax8) {
  __shared__ __align__(16) unsigned char smem[16384];
  const int t = threadIdx.x;
  const int w = t >> 6, l = t & 63;
  const int l15 = l & 15, lq = l >> 4;
  const int tokb = blockIdx.x * 128 + w * 32;
  const int ct0 = blockIdx.y * 8;

  bf16x8 bfr[2][4];
#pragma unroll
  for (int ctile = 0; ctile < 2; ++ctile) {
    const float* row = lat + (size_t)(tokb + ctile * 16 + l15) * DIM;
#pragma unroll
    for (int ks = 0; ks < 4; ++ks) {
      const int d0 = ks * 32 + lq * 4;
      float4 c0 = *(const float4*)(row + d0);
      float4 c1 = *(const float4*)(row + d0 + 16);
      union { ushort4 u4[2]; bf16x8 v; } cv;
      cv.u4[0].x = rne_bf16(c0.x); cv.u4[0].y = rne_bf16(c0.y);
      cv.u4[0].z = rne_bf16(c0.z); cv.u4[0].w = rne_bf16(c0.w);
      cv.u4[1].x = rne_bf16(c1.x); cv.u4[1].y = rne_bf16(c1.y);
      cv.u4[1].z = rne_bf16(c1.z); cv.u4[1].w = rne_bf16(c1.w);
      bfr[ctile][ks] = cv.v;
    }
  }

  for (int it = 0; it < 8; ++it) {
    const int ct = ct0 + it;
    __syncthreads();
    {
      const int r = t & 63, seg = t >> 6;
      const unsigned short* src = cbh + (size_t)(ct * 64 + r) * DIM + seg * 32;
      const int sw = (r & 7) << 4;
#pragma unroll
      for (int i = 0; i < 4; ++i) {
        uint4 v = *(const uint4*)(src + i * 8);
        *(uint4*)(smem + r * 256 + ((seg * 64 + i * 16) ^ sw)) = v;
      }
    }
    __syncthreads();

#pragma unroll
    for (int rt = 0; rt < 4; ++rt) {
      const int row = rt * 16 + l15;
      const int sw = (row & 7) << 4;
      bf16x8 afr[4];
#pragma unroll
      for (int ks = 0; ks < 4; ++ks) {
        const int off = ks * 64 + lq * 8;
        union { uint2 u2[2]; bf16x8 v; } cv;
        cv.u2[0] = *(const uint2*)(smem + row * 256 + (off ^ sw));
        cv.u2[1] = *(const uint2*)(smem + row * 256 + (((off + 32)) ^ sw));
        afr[ks] = cv.v;
      }
#pragma unroll
      for (int ctile = 0; ctile < 2; ++ctile) {
        f32x4 acc = {0.0f, 0.0f, 0.0f, 0.0f};
#pragma unroll
        for (int ks = 0; ks < 4; ++ks)
          acc = __builtin_amdgcn_mfma_f32_16x16x32_bf16(afr[ks], bfr[ctile][ks], acc, 0, 0, 0);
        // per-lane max over 4 codes, pair-combine lq0<->lq1, lq2<->lq3
        float gm = fmaxf(fmaxf(acc[0], acc[1]), fmaxf(acc[2], acc[3]));
        gm = fmaxf(gm, __shfl_xor(gm, 16, 64));
        if ((lq & 1) == 0) {
          const int tok = tokb + ctile * 16 + l15;
          gmax8[(size_t)tok * NG8 + (ct * 8 + rt * 2 + (lq >> 1))] =
              __half_as_ushort(__float2half(gm));
        }
      }
    }
  }
}

// Fused resolve+gather, one wave per token. Scan: one coalesced uint4/lane
// (8 fp16 g8-maxes). thr formula identical to R4-R8. Eval: 8 g8-items x 8
// codes per round; exact per-code chain bit-identical to R1-R8. Inline gather.
__global__ __launch_bounds__(256) void k_resolve(const float* __restrict__ lat,
                                                 const float* __restrict__ cb,
                                                 const float* __restrict__ sumx2,
                                                 const float* __restrict__ sumc2,
                                                 const float* __restrict__ absum,
                                                 const unsigned short* __restrict__ gmax8,
                                                 float* __restrict__ qout,
                                                 float* __restrict__ idx_out,
                                                 float* __restrict__ msum,
                                                 float* __restrict__ csum,
                                                 int* __restrict__ cnt) {
  __shared__ __align__(16) float xs[4][DIM];
  __shared__ unsigned short q[4][NG8];
  __shared__ int qn[4];
  const int w = threadIdx.x >> 6, l = threadIdx.x & 63;
  const int tok = blockIdx.x * 4 + w;

  if (l == 0) qn[w] = 0;
  const float2 xv = *(const float2*)(lat + (size_t)tok * DIM + l * 2);
  const uint4 hv = *(const uint4*)(gmax8 + (size_t)tok * NG8 + l * 8);
  const float sx = sumx2[tok];
  const float ab = absum[tok];
  *(float2*)(&xs[w][l * 2]) = xv;

  float hf[8];
  hf[0] = __half2float(__ushort_as_half((unsigned short)(hv.x & 0xFFFFu)));
  hf[1] = __half2float(__ushort_as_half((unsigned short)(hv.x >> 16)));
  hf[2] = __half2float(__ushort_as_half((unsigned short)(hv.y & 0xFFFFu)));
  hf[3] = __half2float(__ushort_as_half((unsigned short)(hv.y >> 16)));
  hf[4] = __half2float(__ushort_as_half((unsigned short)(hv.z & 0xFFFFu)));
  hf[5] = __half2float(__ushort_as_half((unsigned short)(hv.z >> 16)));
  hf[6] = __half2float(__ushort_as_half((unsigned short)(hv.w & 0xFFFFu)));
  hf[7] = __half2float(__ushort_as_half((unsigned short)(hv.w >> 16)));
  float m = hf[0];
#pragma unroll
  for (int i = 1; i < 8; ++i) m = fmaxf(m, hf[i]);
#pragma unroll
  for (int s = 32; s >= 1; s >>= 1) m = fmaxf(m, __shfl_xor(m, s, 64));
  const float thr = m - (ab * 3.8224e-6f + 6.0e-5f);

  __syncthreads();   // qn init visible
#pragma unroll
  for (int i = 0; i < 8; ++i) {
    if (hf[i] >= thr) {
      const int p = atomicAdd(&qn[w], 1);
      q[w][p] = (unsigned short)(l * 8 + i);
    }
  }
  __syncthreads();

  const int n = qn[w];
  const int slot = l >> 3, cidx = l & 7;
  unsigned long long bestp = ~0ull;
  const float4* xr4 = (const float4*)xs[w];

  for (int base = 0; base < n; base += 8) {
    unsigned long long pack = ~0ull;
    const int qi = base + slot;
    if (qi < n) {
      const int g = (int)q[w][qi];
      const int code = g * 8 + cidx;
      const float4* crow = (const float4*)(cb + (size_t)code * DIM);
      float acc = 0.0f;
#pragma unroll 8
      for (int ch = 0; ch < 32; ++ch) {
        const float4 c = crow[ch];
        const float4 x = xr4[ch];
        acc = fmaf(x.x, c.x, acc); acc = fmaf(x.y, c.y, acc);
        acc = fmaf(x.z, c.z, acc); acc = fmaf(x.w, c.w, acc);
      }
      const float dist = (sx - 2.0f * acc) + sumc2[code];
      pack = ((unsigned long long)__float_as_uint(dist) << 32) | (unsigned)code;
    }
#pragma unroll
    for (int s = 32; s >= 1; s >>= 1) {
      const unsigned long long o = __shfl_xor(pack, s, 64);
      pack = (o < pack) ? o : pack;
    }
    bestp = (pack < bestp) ? pack : bestp;
  }

  // ---- inline gather ----
  const int code = (int)(bestp & 0xFFFFFFFFull);
  const float2 c2 = *(const float2*)(cb + (size_t)code * DIM + l * 2);
  const float o0 = xv.x + (c2.x - xv.x);
  const float o1 = xv.y + (c2.y - xv.y);
  *(float2*)(qout + (size_t)tok * DIM + l * 2) = make_float2(o0, o1);
  const float e0 = xv.x - c2.x, e1 = xv.y - c2.y;
  float msel = e0 * e0 + e1 * e1;
  float dt = xv.x * c2.x + xv.y * c2.y;
#pragma unroll
  for (int s = 32; s >= 1; s >>= 1) {
    msel += __shfl_xor(msel, s, 64);
    dt += __shfl_xor(dt, s, 64);
  }
  if (l == 0) {
    const float nx = fmaxf(sqrtf(sx), 1e-12f);
    const float nc = fmaxf(sqrtf(sumc2[code]), 1e-12f);
    msum[tok] = msel;
    csum[tok] = dt / (nx * nc);
    idx_out[tok] = (float)code;
    atomicAdd(&cnt[code], 1);
  }
}

// Codebook pairwise, single bf16 MFMA pass, fragments direct from global
// (no LDS, no barriers). dot error <= ~1.5e-8 -> d error ~3-7e-6, far below
// the ~2.8e-5 tolerance on min/avg euclidean. Per-wave partials to arrays.
__global__ __launch_bounds__(256) void k_pair_mfma(const unsigned short* __restrict__ cbh,
                                                   const float* __restrict__ sumc2,
                                                   float* __restrict__ pairsum,
                                                   float* __restrict__ pairmin) {
  const int t = threadIdx.x;
  const int w = t >> 6, l = t & 63;
  const int l15 = l & 15, lq = l >> 4;
  const int jb = blockIdx.x * 128 + w * 32;
  const int kb = blockIdx.y * 128;

  bf16x8 bfr[2][4];
#pragma unroll
  for (int ct = 0; ct < 2; ++ct) {
    const unsigned short* rh = cbh + (size_t)(jb + ct * 16 + l15) * DIM;
#pragma unroll
    for (int ks = 0; ks < 4; ++ks) {
      const int d0 = ks * 32 + lq * 4;
      union { ushort4 u4[2]; bf16x8 v; } cvv;
      cvv.u4[0] = *(const ushort4*)(rh + d0);
      cvv.u4[1] = *(const ushort4*)(rh + d0 + 16);
      bfr[ct][ks] = cvv.v;
    }
  }
  const float qj0 = sumc2[jb + l15];
  const float qj1 = sumc2[jb + 16 + l15];
  const int jg0 = jb + l15, jg1 = jb + 16 + l15;

  float lsum = 0.0f, lmin = INFINITY;

#pragma unroll
  for (int kt = 0; kt < 2; ++kt) {
    const int kbase = kb + kt * 64;
#pragma unroll
    for (int rt = 0; rt < 4; ++rt) {
      const unsigned short* rowp = cbh + (size_t)(kbase + rt * 16 + l15) * DIM;
      bf16x8 afr[4];
#pragma unroll
      for (int ks = 0; ks < 4; ++ks) {
        const int d0 = ks * 32 + lq * 4;
        union { ushort4 u4[2]; bf16x8 v; } cvv;
        cvv.u4[0] = *(const ushort4*)(rowp + d0);
        cvv.u4[1] = *(const ushort4*)(rowp + d0 + 16);
        afr[ks] = cvv.v;
      }
      f32x4 aA = {0.0f, 0.0f, 0.0f, 0.0f};
      f32x4 aB = {0.0f, 0.0f, 0.0f, 0.0f};
#pragma unroll
      for (int ks = 0; ks < 4; ++ks) {
        aA = __builtin_amdgcn_mfma_f32_16x16x32_bf16(afr[ks], bfr[0][ks], aA, 0, 0, 0);
        aB = __builtin_amdgcn_mfma_f32_16x16x32_bf16(afr[ks], bfr[1][ks], aB, 0, 0, 0);
      }
      // C/D: row=(lq*4+reg) -> k-code, col=l15 -> j-code [m89]
#pragma unroll
      for (int reg = 0; reg < 4; ++reg) {
        const int krl = rt * 16 + lq * 4 + reg;
        const int kg = kbase + krl;
        const float qk = sumc2[kg];
        const float d2A = (qj0 + qk) - 2.0f * aA[reg];
        const float d2B = (qj1 + qk) - 2.0f * aB[reg];
        const float ddA = sqrtf(fmaxf(d2A, 0.0f));
        const float ddB = sqrtf(fmaxf(d2B, 0.0f));
        lsum += ddA + ddB;
        if (jg0 != kg) lmin = fminf(lmin, ddA);
        if (jg1 != kg) lmin = fminf(lmin, ddB);
      }
    }
  }

#pragma unroll
  for (int s = 32; s >= 1; s >>= 1) {
    lsum += __shfl_xor(lsum, s, 64);
    lmin = fminf(lmin, __shfl_xor(lmin, s, 64));
  }
  if (l == 0) {
    const int slot = (blockIdx.y * 32 + blockIdx.x) * 4 + w;
    pairsum[slot] = lsum;
    pairmin[slot] = lmin;
  }
}

__global__ __launch_bounds__(256) void k_final(const int* __restrict__ cnt,
                                               const float* __restrict__ msum,
                                               const float* __restrict__ csum,
                                               const float* __restrict__ pairsum,
                                               const float* __restrict__ pairmin,
                                               float* __restrict__ outs) {
  __shared__ float sh[256], sh2[256], sh3[256], sh4[256];
  const int t = threadIdx.x;
  float ent = 0.0f;
  for (int k = t; k < KCB; k += 256) {
    const float p = (float)cnt[k] * (1.0f / (float)NTOK);
    ent += p * logf(p + 1e-10f);
  }
  float ms = 0.0f, cs = 0.0f;
  for (int i = t; i < NTOK; i += 256) { ms += msum[i]; cs += csum[i]; }
  float ps = 0.0f, pm = INFINITY;
  for (int i = t; i < 4096; i += 256) { ps += pairsum[i]; pm = fminf(pm, pairmin[i]); }

  sh[t] = ent; sh2[t] = ms; sh3[t] = cs; sh4[t] = ps;
  __syncthreads();
  for (int s = 128; s >= 1; s >>= 1) {
    if (t < s) { sh[t] += sh[t + s]; sh2[t] += sh2[t + s];
                 sh3[t] += sh3[t + s]; sh4[t] += sh4[t + s]; }
    __syncthreads();
  }
  const float ent_tot = sh[0];
  const float ms_tot  = sh2[0];
  const float cs_tot  = sh3[0];
  const float ps_tot  = sh4[0];
  __syncthreads();
  sh[t] = pm;
  __syncthreads();
  for (int s = 128; s >= 1; s >>= 1) {
    if (t < s) sh[t] = fminf(sh[t], sh[t + s]);
    __syncthreads();
  }
  if (t == 0) {
    const float mse = ms_tot * (1.0f / (float)(NTOK * DIM));
    outs[0] = 0.25f * mse;
    outs[1] = mse;
    outs[2] = expf(-ent_tot);
    outs[3] = cs_tot * (1.0f / (float)NTOK);
    outs[4] = ps_tot / ((float)KCB * (float)(KCB - 1));
    outs[5] = sh[0];
  }
}

extern "C" void kernel_launch(void* const* d_in, const int* in_sizes, int n_in,
                              void* d_out, int out_size, void* d_ws, size_t ws_size,
                              hipStream_t stream) {
  const float* lat = (const float*)d_in[0];
  const float* cb  = (const float*)d_in[1];

  float* out     = (float*)d_out;
  float* qout    = out;
  float* idx_out = out + (size_t)NTOK * DIM;
  float* outs    = idx_out + NTOK;

  float* W        = (float*)d_ws;
  float* sumx2    = W;                             // NTOK
  float* sumc2    = sumx2 + NTOK;                  // KCB
  float* absum    = sumc2 + KCB;                   // NTOK
  int*   cnt      = (int*)(absum + NTOK);          // KCB
  float* msum     = (float*)(cnt + KCB);           // NTOK
  float* csum     = msum + NTOK;                   // NTOK
  float* pairsum  = csum + NTOK;                   // 4096
  float* pairmin  = pairsum + 4096;                // 4096
  unsigned short* cbh   = (unsigned short*)(pairmin + 4096);   // KCB*DIM
  unsigned short* gmax8 = cbh + (size_t)KCB * DIM;             // NTOK*NG8

  hipLaunchKernelGGL(k_init, dim3(1), dim3(256), 0, stream, cnt);
  hipLaunchKernelGGL(k_convert, dim3(KCB * DIM / (256 * 8)), dim3(256), 0, stream,
                     cb, cbh);
  hipLaunchKernelGGL(k_rownorm, dim3((NTOK + KCB) / 4), dim3(256), 0, stream,
                     lat, cb, sumx2, sumc2, absum);
  hipLaunchKernelGGL(k_approx, dim3(NTOK / 128, 8), dim3(256), 0, stream,
                     lat, cbh, gmax8);
  hipLaunchKernelGGL(k_resolve, dim3(NTOK / 4), dim3(256), 0, stream,
                     lat, cb, sumx2, sumc2, absum, gmax8,
                     qout, idx_out, msum, csum, cnt);
  hipLaunchKernelGGL(k_pair_mfma, dim3(KCB / 128, KCB / 128), dim3(256), 0, stream,
                     cbh, sumc2, pairsum, pairmin);
  hipLaunchKernelGGL(k_final, dim3(1), dim3(256), 0, stream, cnt,
                     msum, csum, pairsum, pairmin, outs);
}

// Round 10
// 167.669 us; speedup vs baseline: 7.5484x; 1.0006x over previous
//
#include <hip/hip_runtime.h>
#include <hip/hip_fp16.h>
#include <math.h>

#define NTOK 16384
#define KCB  4096
#define DIM  128
#define NG8  (KCB / 8)      // 512 8-code groups

typedef short bf16x8 __attribute__((ext_vector_type(8)));
typedef float f32x4  __attribute__((ext_vector_type(4)));

// RNE float -> bf16 bits
static __device__ inline unsigned short rne_bf16(float f) {
  unsigned u = __float_as_uint(f);
  return (unsigned short)((u + 0x7FFFu + ((u >> 16) & 1u)) >> 16);
}

// ---------------------------------------------------------------------------
// ws layout (float offsets from W):
//   [0]          sumx2[NTOK]
//   +NTOK        sumc2[KCB]
//   +KCB         absum[NTOK]
//   +NTOK        cnt[KCB] (int)
//   +KCB         msum[NTOK]
//   +NTOK        csum[NTOK]
//   +NTOK        pairsum[4096]
//   +4096        pairmin[4096]
//   +4096        cbh[KCB*DIM] (ushort bf16 hi)          = 1 MB
//   +KCB*DIM/2   gmax8[NTOK*NG8] (ushort fp16, row-major per token) = 16.8 MB
// ---------------------------------------------------------------------------

__global__ __launch_bounds__(256) void k_init(int* __restrict__ cnt) {
  const int t = threadIdx.x;
  for (int k = t; k < KCB; k += 256) cnt[k] = 0;
}

// codebook fp32 -> bf16 hi
__global__ __launch_bounds__(256) void k_convert(const float* __restrict__ cb,
                                                 unsigned short* __restrict__ cbh) {
  const int base = (blockIdx.x * 256 + threadIdx.x) * 8;
  float4 v0 = *(const float4*)(cb + base);
  float4 v1 = *(const float4*)(cb + base + 4);
  ushort4 o0, o1;
  o0.x = rne_bf16(v0.x); o0.y = rne_bf16(v0.y); o0.z = rne_bf16(v0.z); o0.w = rne_bf16(v0.w);
  o1.x = rne_bf16(v1.x); o1.y = rne_bf16(v1.y); o1.z = rne_bf16(v1.z); o1.w = rne_bf16(v1.w);
  *(ushort4*)(cbh + base) = o0;
  *(ushort4*)(cbh + base + 4) = o1;
}

__global__ __launch_bounds__(256) void k_rownorm(const float* __restrict__ lat,
                                                 const float* __restrict__ cb,
                                                 float* __restrict__ sumx2,
                                                 float* __restrict__ sumc2,
                                                 float* __restrict__ absum) {
  const int row  = blockIdx.x * 4 + (threadIdx.x >> 6);
  const int lane = threadIdx.x & 63;
  const float* src = (row < NTOK) ? (lat + (size_t)row * DIM)
                                  : (cb + (size_t)(row - NTOK) * DIM);
  float2 v = *(const float2*)(src + lane * 2);
  double s  = (double)v.x * (double)v.x + (double)v.y * (double)v.y;
  double sa = fabs((double)v.x) + fabs((double)v.y);
#pragma unroll
  for (int m = 32; m >= 1; m >>= 1) {
    s  += __shfl_xor(s, m, 64);
    sa += __shfl_xor(sa, m, 64);
  }
  if (lane == 0) {
    if (row < NTOK) { sumx2[row] = (float)s; absum[row] = (float)sa; }
    else            sumc2[row - NTOK] = (float)s;
  }
}

// bf16 MFMA scan. MFMA accs bit-identical to R4-R9. Per-lane g4 max (acc[0..3]
// IS one g4 group -> no cross-lane op), fp16 to LDS transpose buffer; block-end
// writeback combines g4 pairs (fmax of fp16 == fp16 of max, RNE monotone) so
// the emitted gmax8 is bit-identical to R9's, with fully coalesced uint4 stores.
__global__ __launch_bounds__(256) void k_approx(const float* __restrict__ lat,
                                                const unsigned short* __restrict__ cbh,
                                                unsigned short* __restrict__ gmax8) {
  __shared__ __align__(16) unsigned char smem[16384];
  __shared__ __align__(16) unsigned short gbuf[128][72];  // stride 72: bank-spread
  const int t = threadIdx.x;
  const int w = t >> 6, l = t & 63;
  const int l15 = l & 15, lq = l >> 4;
  const int tokb = blockIdx.x * 128 + w * 32;
  const int ct0 = blockIdx.y * 4;

  bf16x8 bfr[2][4];
#pragma unroll
  for (int ctile = 0; ctile < 2; ++ctile) {
    const float* row = lat + (size_t)(tokb + ctile * 16 + l15) * DIM;
#pragma unroll
    for (int ks = 0; ks < 4; ++ks) {
      const int d0 = ks * 32 + lq * 4;
      float4 c0 = *(const float4*)(row + d0);
      float4 c1 = *(const float4*)(row + d0 + 16);
      union { ushort4 u4[2]; bf16x8 v; } cv;
      cv.u4[0].x = rne_bf16(c0.x); cv.u4[0].y = rne_bf16(c0.y);
      cv.u4[0].z = rne_bf16(c0.z); cv.u4[0].w = rne_bf16(c0.w);
      cv.u4[1].x = rne_bf16(c1.x); cv.u4[1].y = rne_bf16(c1.y);
      cv.u4[1].z = rne_bf16(c1.z); cv.u4[1].w = rne_bf16(c1.w);
      bfr[ctile][ks] = cv.v;
    }
  }

  for (int it = 0; it < 4; ++it) {
    const int ct = ct0 + it;
    __syncthreads();
    {
      const int r = t & 63, seg = t >> 6;
      const unsigned short* src = cbh + (size_t)(ct * 64 + r) * DIM + seg * 32;
      const int sw = (r & 7) << 4;
#pragma unroll
      for (int i = 0; i < 4; ++i) {
        uint4 v = *(const uint4*)(src + i * 8);
        *(uint4*)(smem + r * 256 + ((seg * 64 + i * 16) ^ sw)) = v;
      }
    }
    __syncthreads();

#pragma unroll
    for (int rt = 0; rt < 4; ++rt) {
      const int row = rt * 16 + l15;
      const int sw = (row & 7) << 4;
      bf16x8 afr[4];
#pragma unroll
      for (int ks = 0; ks < 4; ++ks) {
        const int off = ks * 64 + lq * 8;
        union { uint2 u2[2]; bf16x8 v; } cv;
        cv.u2[0] = *(const uint2*)(smem + row * 256 + (off ^ sw));
        cv.u2[1] = *(const uint2*)(smem + row * 256 + (((off + 32)) ^ sw));
        afr[ks] = cv.v;
      }
#pragma unroll
      for (int ctile = 0; ctile < 2; ++ctile) {
        f32x4 acc = {0.0f, 0.0f, 0.0f, 0.0f};
#pragma unroll
        for (int ks = 0; ks < 4; ++ks)
          acc = __builtin_amdgcn_mfma_f32_16x16x32_bf16(afr[ks], bfr[ctile][ks], acc, 0, 0, 0);
        // per-lane g4 max: codes (ct*64 + rt*16 + lq*4 + 0..3) for token l15
        const float gm = fmaxf(fmaxf(acc[0], acc[1]), fmaxf(acc[2], acc[3]));
        const int tokl = w * 32 + ctile * 16 + l15;
        gbuf[tokl][it * 16 + rt * 4 + lq] = __half_as_ushort(__float2half(gm));
      }
    }
  }

  __syncthreads();
  // writeback: pack g4 pairs -> g8, coalesced 16B stores
  for (int c = t; c < 512; c += 256) {
    const int token = c >> 2, seg = c & 3;
    const unsigned short* src = &gbuf[token][seg * 16];
    unsigned short in[16];
    *(uint4*)(in)     = *(const uint4*)(src);
    *(uint4*)(in + 8) = *(const uint4*)(src + 8);
    unsigned short o[8];
#pragma unroll
    for (int j = 0; j < 8; ++j) {
      const float f0 = __half2float(__ushort_as_half(in[2 * j]));
      const float f1 = __half2float(__ushort_as_half(in[2 * j + 1]));
      o[j] = __half_as_ushort(__float2half(fmaxf(f0, f1)));
    }
    *(uint4*)(gmax8 + (size_t)(blockIdx.x * 128 + token) * NG8 +
              blockIdx.y * 32 + seg * 8) = *(uint4*)o;
  }
}

// Fused resolve+gather (unchanged from R9 — inputs bit-identical).
__global__ __launch_bounds__(256) void k_resolve(const float* __restrict__ lat,
                                                 const float* __restrict__ cb,
                                                 const float* __restrict__ sumx2,
                                                 const float* __restrict__ sumc2,
                                                 const float* __restrict__ absum,
                                                 const unsigned short* __restrict__ gmax8,
                                                 float* __restrict__ qout,
                                                 float* __restrict__ idx_out,
                                                 float* __restrict__ msum,
                                                 float* __restrict__ csum,
                                                 int* __restrict__ cnt) {
  __shared__ __align__(16) float xs[4][DIM];
  __shared__ unsigned short q[4][NG8];
  __shared__ int qn[4];
  const int w = threadIdx.x >> 6, l = threadIdx.x & 63;
  const int tok = blockIdx.x * 4 + w;

  if (l == 0) qn[w] = 0;
  const float2 xv = *(const float2*)(lat + (size_t)tok * DIM + l * 2);
  const uint4 hv = *(const uint4*)(gmax8 + (size_t)tok * NG8 + l * 8);
  const float sx = sumx2[tok];
  const float ab = absum[tok];
  *(float2*)(&xs[w][l * 2]) = xv;

  float hf[8];
  hf[0] = __half2float(__ushort_as_half((unsigned short)(hv.x & 0xFFFFu)));
  hf[1] = __half2float(__ushort_as_half((unsigned short)(hv.x >> 16)));
  hf[2] = __half2float(__ushort_as_half((unsigned short)(hv.y & 0xFFFFu)));
  hf[3] = __half2float(__ushort_as_half((unsigned short)(hv.y >> 16)));
  hf[4] = __half2float(__ushort_as_half((unsigned short)(hv.z & 0xFFFFu)));
  hf[5] = __half2float(__ushort_as_half((unsigned short)(hv.z >> 16)));
  hf[6] = __half2float(__ushort_as_half((unsigned short)(hv.w & 0xFFFFu)));
  hf[7] = __half2float(__ushort_as_half((unsigned short)(hv.w >> 16)));
  float m = hf[0];
#pragma unroll
  for (int i = 1; i < 8; ++i) m = fmaxf(m, hf[i]);
#pragma unroll
  for (int s = 32; s >= 1; s >>= 1) m = fmaxf(m, __shfl_xor(m, s, 64));
  const float thr = m - (ab * 3.8224e-6f + 6.0e-5f);

  __syncthreads();   // qn init visible
#pragma unroll
  for (int i = 0; i < 8; ++i) {
    if (hf[i] >= thr) {
      const int p = atomicAdd(&qn[w], 1);
      q[w][p] = (unsigned short)(l * 8 + i);
    }
  }
  __syncthreads();

  const int n = qn[w];
  const int slot = l >> 3, cidx = l & 7;
  unsigned long long bestp = ~0ull;
  const float4* xr4 = (const float4*)xs[w];

  for (int base = 0; base < n; base += 8) {
    unsigned long long pack = ~0ull;
    const int qi = base + slot;
    if (qi < n) {
      const int g = (int)q[w][qi];
      const int code = g * 8 + cidx;
      const float4* crow = (const float4*)(cb + (size_t)code * DIM);
      float acc = 0.0f;
#pragma unroll 8
      for (int ch = 0; ch < 32; ++ch) {
        const float4 c = crow[ch];
        const float4 x = xr4[ch];
        acc = fmaf(x.x, c.x, acc); acc = fmaf(x.y, c.y, acc);
        acc = fmaf(x.z, c.z, acc); acc = fmaf(x.w, c.w, acc);
      }
      const float dist = (sx - 2.0f * acc) + sumc2[code];
      pack = ((unsigned long long)__float_as_uint(dist) << 32) | (unsigned)code;
    }
#pragma unroll
    for (int s = 32; s >= 1; s >>= 1) {
      const unsigned long long o = __shfl_xor(pack, s, 64);
      pack = (o < pack) ? o : pack;
    }
    bestp = (pack < bestp) ? pack : bestp;
  }

  // ---- inline gather ----
  const int code = (int)(bestp & 0xFFFFFFFFull);
  const float2 c2 = *(const float2*)(cb + (size_t)code * DIM + l * 2);
  const float o0 = xv.x + (c2.x - xv.x);
  const float o1 = xv.y + (c2.y - xv.y);
  *(float2*)(qout + (size_t)tok * DIM + l * 2) = make_float2(o0, o1);
  const float e0 = xv.x - c2.x, e1 = xv.y - c2.y;
  float msel = e0 * e0 + e1 * e1;
  float dt = xv.x * c2.x + xv.y * c2.y;
#pragma unroll
  for (int s = 32; s >= 1; s >>= 1) {
    msel += __shfl_xor(msel, s, 64);
    dt += __shfl_xor(dt, s, 64);
  }
  if (l == 0) {
    const float nx = fmaxf(sqrtf(sx), 1e-12f);
    const float nc = fmaxf(sqrtf(sumc2[code]), 1e-12f);
    msum[tok] = msel;
    csum[tok] = dt / (nx * nc);
    idx_out[tok] = (float)code;
    atomicAdd(&cnt[code], 1);
  }
}

// Codebook pairwise, single bf16 MFMA pass, fragments direct from global
// (unchanged from R9).
__global__ __launch_bounds__(256) void k_pair_mfma(const unsigned short* __restrict__ cbh,
                                                   const float* __restrict__ sumc2,
                                                   float* __restrict__ pairsum,
                                                   float* __restrict__ pairmin) {
  const int t = threadIdx.x;
  const int w = t >> 6, l = t & 63;
  const int l15 = l & 15, lq = l >> 4;
  const int jb = blockIdx.x * 128 + w * 32;
  const int kb = blockIdx.y * 128;

  bf16x8 bfr[2][4];
#pragma unroll
  for (int ct = 0; ct < 2; ++ct) {
    const unsigned short* rh = cbh + (size_t)(jb + ct * 16 + l15) * DIM;
#pragma unroll
    for (int ks = 0; ks < 4; ++ks) {
      const int d0 = ks * 32 + lq * 4;
      union { ushort4 u4[2]; bf16x8 v; } cvv;
      cvv.u4[0] = *(const ushort4*)(rh + d0);
      cvv.u4[1] = *(const ushort4*)(rh + d0 + 16);
      bfr[ct][ks] = cvv.v;
    }
  }
  const float qj0 = sumc2[jb + l15];
  const float qj1 = sumc2[jb + 16 + l15];
  const int jg0 = jb + l15, jg1 = jb + 16 + l15;

  float lsum = 0.0f, lmin = INFINITY;

#pragma unroll
  for (int kt = 0; kt < 2; ++kt) {
    const int kbase = kb + kt * 64;
#pragma unroll
    for (int rt = 0; rt < 4; ++rt) {
      const unsigned short* rowp = cbh + (size_t)(kbase + rt * 16 + l15) * DIM;
      bf16x8 afr[4];
#pragma unroll
      for (int ks = 0; ks < 4; ++ks) {
        const int d0 = ks * 32 + lq * 4;
        union { ushort4 u4[2]; bf16x8 v; } cvv;
        cvv.u4[0] = *(const ushort4*)(rowp + d0);
        cvv.u4[1] = *(const ushort4*)(rowp + d0 + 16);
        afr[ks] = cvv.v;
      }
      f32x4 aA = {0.0f, 0.0f, 0.0f, 0.0f};
      f32x4 aB = {0.0f, 0.0f, 0.0f, 0.0f};
#pragma unroll
      for (int ks = 0; ks < 4; ++ks) {
        aA = __builtin_amdgcn_mfma_f32_16x16x32_bf16(afr[ks], bfr[0][ks], aA, 0, 0, 0);
        aB = __builtin_amdgcn_mfma_f32_16x16x32_bf16(afr[ks], bfr[1][ks], aB, 0, 0, 0);
      }
#pragma unroll
      for (int reg = 0; reg < 4; ++reg) {
        const int krl = rt * 16 + lq * 4 + reg;
        const int kg = kbase + krl;
        const float qk = sumc2[kg];
        const float d2A = (qj0 + qk) - 2.0f * aA[reg];
        const float d2B = (qj1 + qk) - 2.0f * aB[reg];
        const float ddA = sqrtf(fmaxf(d2A, 0.0f));
        const float ddB = sqrtf(fmaxf(d2B, 0.0f));
        lsum += ddA + ddB;
        if (jg0 != kg) lmin = fminf(lmin, ddA);
        if (jg1 != kg) lmin = fminf(lmin, ddB);
      }
    }
  }

#pragma unroll
  for (int s = 32; s >= 1; s >>= 1) {
    lsum += __shfl_xor(lsum, s, 64);
    lmin = fminf(lmin, __shfl_xor(lmin, s, 64));
  }
  if (l == 0) {
    const int slot = (blockIdx.y * 32 + blockIdx.x) * 4 + w;
    pairsum[slot] = lsum;
    pairmin[slot] = lmin;
  }
}

__global__ __launch_bounds__(256) void k_final(const int* __restrict__ cnt,
                                               const float* __restrict__ msum,
                                               const float* __restrict__ csum,
                                               const float* __restrict__ pairsum,
                                               const float* __restrict__ pairmin,
                                               float* __restrict__ outs) {
  __shared__ float sh[256], sh2[256], sh3[256], sh4[256];
  const int t = threadIdx.x;
  float ent = 0.0f;
  for (int k = t; k < KCB; k += 256) {
    const float p = (float)cnt[k] * (1.0f / (float)NTOK);
    ent += p * logf(p + 1e-10f);
  }
  float ms = 0.0f, cs = 0.0f;
  for (int i = t; i < NTOK; i += 256) { ms += msum[i]; cs += csum[i]; }
  float ps = 0.0f, pm = INFINITY;
  for (int i = t; i < 4096; i += 256) { ps += pairsum[i]; pm = fminf(pm, pairmin[i]); }

  sh[t] = ent; sh2[t] = ms; sh3[t] = cs; sh4[t] = ps;
  __syncthreads();
  for (int s = 128; s >= 1; s >>= 1) {
    if (t < s) { sh[t] += sh[t + s]; sh2[t] += sh2[t + s];
                 sh3[t] += sh3[t + s]; sh4[t] += sh4[t + s]; }
    __syncthreads();
  }
  const float ent_tot = sh[0];
  const float ms_tot  = sh2[0];
  const float cs_tot  = sh3[0];
  const float ps_tot  = sh4[0];
  __syncthreads();
  sh[t] = pm;
  __syncthreads();
  for (int s = 128; s >= 1; s >>= 1) {
    if (t < s) sh[t] = fminf(sh[t], sh[t + s]);
    __syncthreads();
  }
  if (t == 0) {
    const float mse = ms_tot * (1.0f / (float)(NTOK * DIM));
    outs[0] = 0.25f * mse;
    outs[1] = mse;
    outs[2] = expf(-ent_tot);
    outs[3] = cs_tot * (1.0f / (float)NTOK);
    outs[4] = ps_tot / ((float)KCB * (float)(KCB - 1));
    outs[5] = sh[0];
  }
}

extern "C" void kernel_launch(void* const* d_in, const int* in_sizes, int n_in,
                              void* d_out, int out_size, void* d_ws, size_t ws_size,
                              hipStream_t stream) {
  const float* lat = (const float*)d_in[0];
  const float* cb  = (const float*)d_in[1];

  float* out     = (float*)d_out;
  float* qout    = out;
  float* idx_out = out + (size_t)NTOK * DIM;
  float* outs    = idx_out + NTOK;

  float* W        = (float*)d_ws;
  float* sumx2    = W;                             // NTOK
  float* sumc2    = sumx2 + NTOK;                  // KCB
  float* absum    = sumc2 + KCB;                   // NTOK
  int*   cnt      = (int*)(absum + NTOK);          // KCB
  float* msum     = (float*)(cnt + KCB);           // NTOK
  float* csum     = msum + NTOK;                   // NTOK
  float* pairsum  = csum + NTOK;                   // 4096
  float* pairmin  = pairsum + 4096;                // 4096
  unsigned short* cbh   = (unsigned short*)(pairmin + 4096);   // KCB*DIM
  unsigned short* gmax8 = cbh + (size_t)KCB * DIM;             // NTOK*NG8

  hipLaunchKernelGGL(k_init, dim3(1), dim3(256), 0, stream, cnt);
  hipLaunchKernelGGL(k_convert, dim3(KCB * DIM / (256 * 8)), dim3(256), 0, stream,
                     cb, cbh);
  hipLaunchKernelGGL(k_rownorm, dim3((NTOK + KCB) / 4), dim3(256), 0, stream,
                     lat, cb, sumx2, sumc2, absum);
  hipLaunchKernelGGL(k_approx, dim3(NTOK / 128, 16), dim3(256), 0, stream,
                     lat, cbh, gmax8);
  hipLaunchKernelGGL(k_resolve, dim3(NTOK / 4), dim3(256), 0, stream,
                     lat, cb, sumx2, sumc2, absum, gmax8,
                     qout, idx_out, msum, csum, cnt);
  hipLaunchKernelGGL(k_pair_mfma, dim3(KCB / 128, KCB / 128), dim3(256), 0, stream,
                     cbh, sumc2, pairsum, pairmin);
  hipLaunchKernelGGL(k_final, dim3(1), dim3(256), 0, stream, cnt,
                     msum, csum, pairsum, pairmin, outs);
}

// Round 11
// 140.395 us; speedup vs baseline: 9.0148x; 1.1943x over previous
//
#include <hip/hip_runtime.h>
#include <hip/hip_fp16.h>
#include <math.h>

#define NTOK 16384
#define KCB  4096
#define DIM  128
#define NG8  (KCB / 8)      // 512 8-code groups

typedef short bf16x8 __attribute__((ext_vector_type(8)));
typedef float f32x4  __attribute__((ext_vector_type(4)));

// RNE float -> bf16 bits
static __device__ inline unsigned short rne_bf16(float f) {
  unsigned u = __float_as_uint(f);
  return (unsigned short)((u + 0x7FFFu + ((u >> 16) & 1u)) >> 16);
}

// ---------------------------------------------------------------------------
// ws layout (float offsets from W):
//   [0]          sumx2[NTOK]
//   +NTOK        sumc2[KCB]
//   +KCB         absum[NTOK]
//   +NTOK        cnt[KCB] (int)
//   +KCB         msum[NTOK]
//   +NTOK        csum[NTOK]
//   +NTOK        pairsum[4096]
//   +4096        pairmin[4096]
//   +4096        cbh[KCB*DIM] (ushort bf16 hi)
//   +KCB*DIM/2   gmax8[NTOK*NG8] (ushort fp16, row-major per token)
// ---------------------------------------------------------------------------

// codebook fp32 -> bf16 hi
__global__ __launch_bounds__(256) void k_convert(const float* __restrict__ cb,
                                                 unsigned short* __restrict__ cbh) {
  const int base = (blockIdx.x * 256 + threadIdx.x) * 8;
  float4 v0 = *(const float4*)(cb + base);
  float4 v1 = *(const float4*)(cb + base + 4);
  ushort4 o0, o1;
  o0.x = rne_bf16(v0.x); o0.y = rne_bf16(v0.y); o0.z = rne_bf16(v0.z); o0.w = rne_bf16(v0.w);
  o1.x = rne_bf16(v1.x); o1.y = rne_bf16(v1.y); o1.z = rne_bf16(v1.z); o1.w = rne_bf16(v1.w);
  *(ushort4*)(cbh + base) = o0;
  *(ushort4*)(cbh + base + 4) = o1;
}

// rownorm + cnt zeroing (folded k_init)
__global__ __launch_bounds__(256) void k_rownorm(const float* __restrict__ lat,
                                                 const float* __restrict__ cb,
                                                 float* __restrict__ sumx2,
                                                 float* __restrict__ sumc2,
                                                 float* __restrict__ absum,
                                                 int* __restrict__ cnt) {
  if (blockIdx.x < 16) cnt[blockIdx.x * 256 + threadIdx.x] = 0;
  const int row  = blockIdx.x * 4 + (threadIdx.x >> 6);
  const int lane = threadIdx.x & 63;
  const float* src = (row < NTOK) ? (lat + (size_t)row * DIM)
                                  : (cb + (size_t)(row - NTOK) * DIM);
  float2 v = *(const float2*)(src + lane * 2);
  double s  = (double)v.x * (double)v.x + (double)v.y * (double)v.y;
  double sa = fabs((double)v.x) + fabs((double)v.y);
#pragma unroll
  for (int m = 32; m >= 1; m >>= 1) {
    s  += __shfl_xor(s, m, 64);
    sa += __shfl_xor(sa, m, 64);
  }
  if (lane == 0) {
    if (row < NTOK) { sumx2[row] = (float)s; absum[row] = (float)sa; }
    else            sumc2[row - NTOK] = (float)s;
  }
}

// bf16 MFMA scan. 256 tokens/block: each wave holds 4 token-ctiles in regs ->
// 16 MFMA (4 independent chains) per afr load, half the barriers per MFMA.
// Fragments/ks-order/g4-max/writeback unchanged -> gmax8 bit-identical to R10.
__global__ __launch_bounds__(256) void k_approx(const float* __restrict__ lat,
                                                const unsigned short* __restrict__ cbh,
                                                unsigned short* __restrict__ gmax8) {
  __shared__ __align__(16) unsigned char smem[16384];
  __shared__ __align__(16) unsigned short gbuf[256][72];
  const int t = threadIdx.x;
  const int w = t >> 6, l = t & 63;
  const int l15 = l & 15, lq = l >> 4;
  const int tokb = blockIdx.x * 256 + w * 64;
  const int ct0 = blockIdx.y * 4;

  bf16x8 bfr[4][4];
#pragma unroll
  for (int ctile = 0; ctile < 4; ++ctile) {
    const float* row = lat + (size_t)(tokb + ctile * 16 + l15) * DIM;
#pragma unroll
    for (int ks = 0; ks < 4; ++ks) {
      const int d0 = ks * 32 + lq * 4;
      float4 c0 = *(const float4*)(row + d0);
      float4 c1 = *(const float4*)(row + d0 + 16);
      union { ushort4 u4[2]; bf16x8 v; } cv;
      cv.u4[0].x = rne_bf16(c0.x); cv.u4[0].y = rne_bf16(c0.y);
      cv.u4[0].z = rne_bf16(c0.z); cv.u4[0].w = rne_bf16(c0.w);
      cv.u4[1].x = rne_bf16(c1.x); cv.u4[1].y = rne_bf16(c1.y);
      cv.u4[1].z = rne_bf16(c1.z); cv.u4[1].w = rne_bf16(c1.w);
      bfr[ctile][ks] = cv.v;
    }
  }

  for (int it = 0; it < 4; ++it) {
    const int ct = ct0 + it;
    __syncthreads();
    {
      const int r = t & 63, seg = t >> 6;
      const unsigned short* src = cbh + (size_t)(ct * 64 + r) * DIM + seg * 32;
      const int sw = (r & 7) << 4;
#pragma unroll
      for (int i = 0; i < 4; ++i) {
        uint4 v = *(const uint4*)(src + i * 8);
        *(uint4*)(smem + r * 256 + ((seg * 64 + i * 16) ^ sw)) = v;
      }
    }
    __syncthreads();

#pragma unroll
    for (int rt = 0; rt < 4; ++rt) {
      const int row = rt * 16 + l15;
      const int sw = (row & 7) << 4;
      bf16x8 afr[4];
#pragma unroll
      for (int ks = 0; ks < 4; ++ks) {
        const int off = ks * 64 + lq * 8;
        union { uint2 u2[2]; bf16x8 v; } cv;
        cv.u2[0] = *(const uint2*)(smem + row * 256 + (off ^ sw));
        cv.u2[1] = *(const uint2*)(smem + row * 256 + (((off + 32)) ^ sw));
        afr[ks] = cv.v;
      }
      f32x4 acc[4];
#pragma unroll
      for (int c = 0; c < 4; ++c) acc[c] = (f32x4){0.0f, 0.0f, 0.0f, 0.0f};
#pragma unroll
      for (int ks = 0; ks < 4; ++ks)     // ks outer, ctile inner: 4 indep chains
#pragma unroll
        for (int c = 0; c < 4; ++c)
          acc[c] = __builtin_amdgcn_mfma_f32_16x16x32_bf16(afr[ks], bfr[c][ks], acc[c], 0, 0, 0);
#pragma unroll
      for (int c = 0; c < 4; ++c) {
        const float gm = fmaxf(fmaxf(acc[c][0], acc[c][1]), fmaxf(acc[c][2], acc[c][3]));
        const int tokl = w * 64 + c * 16 + l15;
        gbuf[tokl][it * 16 + rt * 4 + lq] = __half_as_ushort(__float2half(gm));
      }
    }
  }

  __syncthreads();
  // writeback: pack g4 pairs -> g8, coalesced 16B stores
  for (int c = t; c < 1024; c += 256) {
    const int token = c >> 2, seg = c & 3;
    const unsigned short* src = &gbuf[token][seg * 16];
    unsigned short in[16];
    *(uint4*)(in)     = *(const uint4*)(src);
    *(uint4*)(in + 8) = *(const uint4*)(src + 8);
    unsigned short o[8];
#pragma unroll
    for (int j = 0; j < 8; ++j) {
      const float f0 = __half2float(__ushort_as_half(in[2 * j]));
      const float f1 = __half2float(__ushort_as_half(in[2 * j + 1]));
      o[j] = __half_as_ushort(__float2half(fmaxf(f0, f1)));
    }
    *(uint4*)(gmax8 + (size_t)(blockIdx.x * 256 + token) * NG8 +
              blockIdx.y * 32 + seg * 8) = *(uint4*)o;
  }
}

// Fused resolve+gather (unchanged from R9/R10 — inputs bit-identical).
__global__ __launch_bounds__(256) void k_resolve(const float* __restrict__ lat,
                                                 const float* __restrict__ cb,
                                                 const float* __restrict__ sumx2,
                                                 const float* __restrict__ sumc2,
                                                 const float* __restrict__ absum,
                                                 const unsigned short* __restrict__ gmax8,
                                                 float* __restrict__ qout,
                                                 float* __restrict__ idx_out,
                                                 float* __restrict__ msum,
                                                 float* __restrict__ csum,
                                                 int* __restrict__ cnt) {
  __shared__ __align__(16) float xs[4][DIM];
  __shared__ unsigned short q[4][NG8];
  __shared__ int qn[4];
  const int w = threadIdx.x >> 6, l = threadIdx.x & 63;
  const int tok = blockIdx.x * 4 + w;

  if (l == 0) qn[w] = 0;
  const float2 xv = *(const float2*)(lat + (size_t)tok * DIM + l * 2);
  const uint4 hv = *(const uint4*)(gmax8 + (size_t)tok * NG8 + l * 8);
  const float sx = sumx2[tok];
  const float ab = absum[tok];
  *(float2*)(&xs[w][l * 2]) = xv;

  float hf[8];
  hf[0] = __half2float(__ushort_as_half((unsigned short)(hv.x & 0xFFFFu)));
  hf[1] = __half2float(__ushort_as_half((unsigned short)(hv.x >> 16)));
  hf[2] = __half2float(__ushort_as_half((unsigned short)(hv.y & 0xFFFFu)));
  hf[3] = __half2float(__ushort_as_half((unsigned short)(hv.y >> 16)));
  hf[4] = __half2float(__ushort_as_half((unsigned short)(hv.z & 0xFFFFu)));
  hf[5] = __half2float(__ushort_as_half((unsigned short)(hv.z >> 16)));
  hf[6] = __half2float(__ushort_as_half((unsigned short)(hv.w & 0xFFFFu)));
  hf[7] = __half2float(__ushort_as_half((unsigned short)(hv.w >> 16)));
  float m = hf[0];
#pragma unroll
  for (int i = 1; i < 8; ++i) m = fmaxf(m, hf[i]);
#pragma unroll
  for (int s = 32; s >= 1; s >>= 1) m = fmaxf(m, __shfl_xor(m, s, 64));
  const float thr = m - (ab * 3.8224e-6f + 6.0e-5f);

  __syncthreads();   // qn init visible
#pragma unroll
  for (int i = 0; i < 8; ++i) {
    if (hf[i] >= thr) {
      const int p = atomicAdd(&qn[w], 1);
      q[w][p] = (unsigned short)(l * 8 + i);
    }
  }
  __syncthreads();

  const int n = qn[w];
  const int slot = l >> 3, cidx = l & 7;
  unsigned long long bestp = ~0ull;
  const float4* xr4 = (const float4*)xs[w];

  for (int base = 0; base < n; base += 8) {
    unsigned long long pack = ~0ull;
    const int qi = base + slot;
    if (qi < n) {
      const int g = (int)q[w][qi];
      const int code = g * 8 + cidx;
      const float4* crow = (const float4*)(cb + (size_t)code * DIM);
      float acc = 0.0f;
#pragma unroll 8
      for (int ch = 0; ch < 32; ++ch) {
        const float4 c = crow[ch];
        const float4 x = xr4[ch];
        acc = fmaf(x.x, c.x, acc); acc = fmaf(x.y, c.y, acc);
        acc = fmaf(x.z, c.z, acc); acc = fmaf(x.w, c.w, acc);
      }
      const float dist = (sx - 2.0f * acc) + sumc2[code];
      pack = ((unsigned long long)__float_as_uint(dist) << 32) | (unsigned)code;
    }
#pragma unroll
    for (int s = 32; s >= 1; s >>= 1) {
      const unsigned long long o = __shfl_xor(pack, s, 64);
      pack = (o < pack) ? o : pack;
    }
    bestp = (pack < bestp) ? pack : bestp;
  }

  // ---- inline gather ----
  const int code = (int)(bestp & 0xFFFFFFFFull);
  const float2 c2 = *(const float2*)(cb + (size_t)code * DIM + l * 2);
  const float o0 = xv.x + (c2.x - xv.x);
  const float o1 = xv.y + (c2.y - xv.y);
  *(float2*)(qout + (size_t)tok * DIM + l * 2) = make_float2(o0, o1);
  const float e0 = xv.x - c2.x, e1 = xv.y - c2.y;
  float msel = e0 * e0 + e1 * e1;
  float dt = xv.x * c2.x + xv.y * c2.y;
#pragma unroll
  for (int s = 32; s >= 1; s >>= 1) {
    msel += __shfl_xor(msel, s, 64);
    dt += __shfl_xor(dt, s, 64);
  }
  if (l == 0) {
    const float nx = fmaxf(sqrtf(sx), 1e-12f);
    const float nc = fmaxf(sqrtf(sumc2[code]), 1e-12f);
    msum[tok] = msel;
    csum[tok] = dt / (nx * nc);
    idx_out[tok] = (float)code;
    atomicAdd(&cnt[code], 1);
  }
}

// Codebook pairwise: block = 256 j-codes (4 ctiles/wave in regs) x one
// 64-k-code LDS-staged tile (coalesced, swizzled). One barrier; 64 MFMA/wave
// with 4 independent chains. Same fragment k-layout & C/D mapping as R9/R10.
__global__ __launch_bounds__(256) void k_pair_mfma(const unsigned short* __restrict__ cbh,
                                                   const float* __restrict__ sumc2,
                                                   float* __restrict__ pairsum,
                                                   float* __restrict__ pairmin) {
  __shared__ __align__(16) unsigned char smem[16384];
  __shared__ float qs[64];
  const int t = threadIdx.x;
  const int w = t >> 6, l = t & 63;
  const int l15 = l & 15, lq = l >> 4;
  const int jb = blockIdx.x * 256 + w * 64;
  const int kb = blockIdx.y * 64;

  {  // stage k-tile (64 codes x 128 bf16, swizzled) + qs
    const int r = t & 63, seg = t >> 6;
    const unsigned short* src = cbh + (size_t)(kb + r) * DIM + seg * 32;
    const int sw = (r & 7) << 4;
#pragma unroll
    for (int i = 0; i < 4; ++i) {
      uint4 v = *(const uint4*)(src + i * 8);
      *(uint4*)(smem + r * 256 + ((seg * 64 + i * 16) ^ sw)) = v;
    }
    if (t < 64) qs[t] = sumc2[kb + t];
  }

  bf16x8 bfr[4][4];
  float qj[4];
#pragma unroll
  for (int ct = 0; ct < 4; ++ct) {
    const unsigned short* rh = cbh + (size_t)(jb + ct * 16 + l15) * DIM;
#pragma unroll
    for (int ks = 0; ks < 4; ++ks) {
      const int d0 = ks * 32 + lq * 4;
      union { ushort4 u4[2]; bf16x8 v; } cvv;
      cvv.u4[0] = *(const ushort4*)(rh + d0);
      cvv.u4[1] = *(const ushort4*)(rh + d0 + 16);
      bfr[ct][ks] = cvv.v;
    }
    qj[ct] = sumc2[jb + ct * 16 + l15];
  }
  __syncthreads();

  float lsum = 0.0f, lmin = INFINITY;

#pragma unroll
  for (int rt = 0; rt < 4; ++rt) {
    const int row = rt * 16 + l15;
    const int sw = (row & 7) << 4;
    bf16x8 afr[4];
#pragma unroll
    for (int ks = 0; ks < 4; ++ks) {
      const int off = ks * 64 + lq * 8;
      union { uint2 u2[2]; bf16x8 v; } cv;
      cv.u2[0] = *(const uint2*)(smem + row * 256 + (off ^ sw));
      cv.u2[1] = *(const uint2*)(smem + row * 256 + (((off + 32)) ^ sw));
      afr[ks] = cv.v;
    }
    f32x4 acc[4];
#pragma unroll
    for (int c = 0; c < 4; ++c) acc[c] = (f32x4){0.0f, 0.0f, 0.0f, 0.0f};
#pragma unroll
    for (int ks = 0; ks < 4; ++ks)
#pragma unroll
      for (int c = 0; c < 4; ++c)
        acc[c] = __builtin_amdgcn_mfma_f32_16x16x32_bf16(afr[ks], bfr[c][ks], acc[c], 0, 0, 0);

#pragma unroll
    for (int c = 0; c < 4; ++c) {
      const int jg = jb + c * 16 + l15;
#pragma unroll
      for (int reg = 0; reg < 4; ++reg) {
        const int krl = rt * 16 + lq * 4 + reg;
        const int kg = kb + krl;
        const float d2 = (qj[c] + qs[krl]) - 2.0f * acc[c][reg];
        const float dd = sqrtf(fmaxf(d2, 0.0f));
        lsum += dd;
        if (jg != kg) lmin = fminf(lmin, dd);
      }
    }
  }

#pragma unroll
  for (int s = 32; s >= 1; s >>= 1) {
    lsum += __shfl_xor(lsum, s, 64);
    lmin = fminf(lmin, __shfl_xor(lmin, s, 64));
  }
  if (l == 0) {
    const int slot = (blockIdx.y * 16 + blockIdx.x) * 4 + w;
    pairsum[slot] = lsum;
    pairmin[slot] = lmin;
  }
}

__global__ __launch_bounds__(256) void k_final(const int* __restrict__ cnt,
                                               const float* __restrict__ msum,
                                               const float* __restrict__ csum,
                                               const float* __restrict__ pairsum,
                                               const float* __restrict__ pairmin,
                                               float* __restrict__ outs) {
  __shared__ float sh[256], sh2[256], sh3[256], sh4[256];
  const int t = threadIdx.x;
  float ent = 0.0f;
  for (int k = t; k < KCB; k += 256) {
    const float p = (float)cnt[k] * (1.0f / (float)NTOK);
    ent += p * logf(p + 1e-10f);
  }
  float ms = 0.0f, cs = 0.0f;
  for (int i = t; i < NTOK; i += 256) { ms += msum[i]; cs += csum[i]; }
  float ps = 0.0f, pm = INFINITY;
  for (int i = t; i < 4096; i += 256) { ps += pairsum[i]; pm = fminf(pm, pairmin[i]); }

  sh[t] = ent; sh2[t] = ms; sh3[t] = cs; sh4[t] = ps;
  __syncthreads();
  for (int s = 128; s >= 1; s >>= 1) {
    if (t < s) { sh[t] += sh[t + s]; sh2[t] += sh2[t + s];
                 sh3[t] += sh3[t + s]; sh4[t] += sh4[t + s]; }
    __syncthreads();
  }
  const float ent_tot = sh[0];
  const float ms_tot  = sh2[0];
  const float cs_tot  = sh3[0];
  const float ps_tot  = sh4[0];
  __syncthreads();
  sh[t] = pm;
  __syncthreads();
  for (int s = 128; s >= 1; s >>= 1) {
    if (t < s) sh[t] = fminf(sh[t], sh[t + s]);
    __syncthreads();
  }
  if (t == 0) {
    const float mse = ms_tot * (1.0f / (float)(NTOK * DIM));
    outs[0] = 0.25f * mse;
    outs[1] = mse;
    outs[2] = expf(-ent_tot);
    outs[3] = cs_tot * (1.0f / (float)NTOK);
    outs[4] = ps_tot / ((float)KCB * (float)(KCB - 1));
    outs[5] = sh[0];
  }
}

extern "C" void kernel_launch(void* const* d_in, const int* in_sizes, int n_in,
                              void* d_out, int out_size, void* d_ws, size_t ws_size,
                              hipStream_t stream) {
  const float* lat = (const float*)d_in[0];
  const float* cb  = (const float*)d_in[1];

  float* out     = (float*)d_out;
  float* qout    = out;
  float* idx_out = out + (size_t)NTOK * DIM;
  float* outs    = idx_out + NTOK;

  float* W        = (float*)d_ws;
  float* sumx2    = W;                             // NTOK
  float* sumc2    = sumx2 + NTOK;                  // KCB
  float* absum    = sumc2 + KCB;                   // NTOK
  int*   cnt      = (int*)(absum + NTOK);          // KCB
  float* msum     = (float*)(cnt + KCB);           // NTOK
  float* csum     = msum + NTOK;                   // NTOK
  float* pairsum  = csum + NTOK;                   // 4096
  float* pairmin  = pairsum + 4096;                // 4096
  unsigned short* cbh   = (unsigned short*)(pairmin + 4096);   // KCB*DIM
  unsigned short* gmax8 = cbh + (size_t)KCB * DIM;             // NTOK*NG8

  hipLaunchKernelGGL(k_convert, dim3(KCB * DIM / (256 * 8)), dim3(256), 0, stream,
                     cb, cbh);
  hipLaunchKernelGGL(k_rownorm, dim3((NTOK + KCB) / 4), dim3(256), 0, stream,
                     lat, cb, sumx2, sumc2, absum, cnt);
  hipLaunchKernelGGL(k_approx, dim3(NTOK / 256, 16), dim3(256), 0, stream,
                     lat, cbh, gmax8);
  hipLaunchKernelGGL(k_resolve, dim3(NTOK / 4), dim3(256), 0, stream,
                     lat, cb, sumx2, sumc2, absum, gmax8,
                     qout, idx_out, msum, csum, cnt);
  hipLaunchKernelGGL(k_pair_mfma, dim3(KCB / 256, KCB / 64), dim3(256), 0, stream,
                     cbh, sumc2, pairsum, pairmin);
  hipLaunchKernelGGL(k_final, dim3(1), dim3(256), 0, stream, cnt,
                     msum, csum, pairsum, pairmin, outs);
}